// Round 10
// baseline (223.238 us; speedup 1.0000x reference)
//
#include <hip/hip_runtime.h>
#include <math.h>

#define N_NODES  20000
#define N_EDGES  320000
#define N_GRAPHS 200
#define MAXN     100
#define F_IN     128
#define F_H      256
#define F_L      64
#define P_PAIRS  4950
#define P_PAD    4992                       // P_PAIRS padded to multiple of 64
#define ADJ_SIZE (N_GRAPHS * MAXN * MAXN)   // 2,000,000
#define MU_OFF   ADJ_SIZE
#define LV_OFF   (ADJ_SIZE + N_GRAPHS * F_L)

#define ELL_W    64                         // ELL row capacity (deg ~ Poisson(16); 64 = ~12 sigma)
#define EF_NB    ((N_EDGES + 255) / 256)    // 1250 edge-fill blocks

static inline int ceil_div(int a, int b) { return (a + b - 1) / b; }

typedef __attribute__((ext_vector_type(8))) short bf16x8;   // 4 VGPRs
typedef __attribute__((ext_vector_type(4))) float f32x4;    // MFMA acc

// fp32 -> bf16 round-to-nearest-even
static __device__ inline unsigned short f2bf(float f) {
    union { float f; unsigned u; } v; v.f = f;
    unsigned r = (v.u + 0x7FFFu + ((v.u >> 16) & 1u)) >> 16;
    return (unsigned short)r;
}
static __device__ inline float bf2f(unsigned short s) {
    union { unsigned u; float f; } v; v.u = (unsigned)s << 16; return v.f;
}
static __device__ inline float4 ubf4(ushort4 u) {
    float4 f;
    f.x = bf2f(u.x); f.y = bf2f(u.y); f.z = bf2f(u.z); f.w = bf2f(u.w);
    return f;
}
static __device__ inline float rdeg(int d) { return rsqrtf((float)d + 1.0f); }  // +1 self-loop

// ---------------------------------------------------------------- fused ELL fill + weight prepack + xs cast
#define PP_S1  32768                       // W1: 128*256
#define PP_S2  98304                       // + W2: 256*256
#define PP_END 1376256                     // + D3: 256*4992
#define PP_NB  (PP_END / 256)              // 5376
#define CV_END 640000                      // N_NODES*F_IN/4 float4 elements
#define CV_NB  (CV_END / 256)              // 2500
__global__ __launch_bounds__(256) void k_prep(
        const int* __restrict__ src, const int* __restrict__ dst,
        int* __restrict__ fill, int* __restrict__ ell,
        const float* __restrict__ W1, const float* __restrict__ W2,
        const float* __restrict__ D3,
        unsigned short* __restrict__ W1p, unsigned short* __restrict__ W2p,
        unsigned short* __restrict__ D3p,
        const float* __restrict__ x, unsigned short* __restrict__ xs) {
    if (blockIdx.x < EF_NB) {
        int e = blockIdx.x * 256 + threadIdx.x;
        if (e < N_EDGES) {
            int d = dst[e];
            int pos = atomicAdd(fill + d, 1);
            if (pos < ELL_W) ell[d * ELL_W + pos] = src[e];
        }
        return;
    }
    if (blockIdx.x < EF_NB + PP_NB) {
        int pid = (blockIdx.x - EF_NB) * 256 + threadIdx.x;
        const float* W; unsigned short* Bp; int N, NP, t;
        if (pid < PP_S1)      { t = pid;          W = W1; Bp = W1p; N = 256;     NP = 256; }
        else if (pid < PP_S2) { t = pid - PP_S1;  W = W2; Bp = W2p; N = 256;     NP = 256; }
        else                  { t = pid - PP_S2;  W = D3; Bp = D3p; N = P_PAIRS; NP = P_PAD; }
        int j    = t & 7;
        int lane = (t >> 3) & 63;
        int tile = t >> 9;
        int NT = NP >> 4;
        int nt = tile % NT;
        int kt = tile / NT;
        int k = kt * 32 + (lane >> 4) * 8 + j;
        int n = nt * 16 + (lane & 15);
        Bp[t] = (n < N) ? f2bf(W[(size_t)k * N + n]) : (unsigned short)0;
        return;
    }
    int tid = (blockIdx.x - EF_NB - PP_NB) * 256 + threadIdx.x;
    if (tid >= CV_END) return;
    float4 val = ((const float4*)x)[tid];
    ushort4 o;
    o.x = f2bf(val.x); o.y = f2bf(val.y);
    o.z = f2bf(val.z); o.w = f2bf(val.w);
    ((ushort4*)xs)[tid] = o;
}

// ---------------------------------------------------------------- fused layer 1: gather(x) + MFMA
// Block: 32 nodes x 256 outputs, 512 threads = 8 waves -> 625 blocks, 5000 waves.
// Gather inner loop 16-deep (mean row = 16 edges -> one batch covers typical row;
// 2x outstanding loads per wave vs R9's 8-deep).
__global__ __launch_bounds__(512) void k_layer1(const unsigned short* __restrict__ xs,
                                                const int* __restrict__ fill,
                                                const int* __restrict__ ell,
                                                const unsigned short* __restrict__ W1p,
                                                const float* __restrict__ bias,
                                                unsigned short* __restrict__ h1s, int M) {
    __shared__ unsigned short At[32 * 128];     // 8 KB, byte-XOR swizzled
    char* Ab = (char*)At;
    const int tid  = threadIdx.x;
    const int lane = tid & 63;
    const int w    = tid >> 6;                  // 0..7

    // ---- gather phase: 4 nodes per wave, lanes cover 128 feats as ushort2
    for (int s = 0; s < 4; ++s) {
        int slot = w * 4 + s;                   // 0..31
        int v = blockIdx.x * 32 + slot;
        ushort2 ob; ob.x = 0; ob.y = 0;
        if (v < M) {
            int dg  = fill[v];
            int beg = v * ELL_W;
            int end = beg + min(dg, ELL_W);
            float dv = rdeg(dg);
            float2 a0 = make_float2(0.f, 0.f), a1 = make_float2(0.f, 0.f);
            float2 a2 = make_float2(0.f, 0.f), a3 = make_float2(0.f, 0.f);
            int i = beg;
            for (; i + 16 <= end; i += 16) {
                int t0 = ell[i + 0],  t1 = ell[i + 1],  t2 = ell[i + 2],  t3 = ell[i + 3];
                int t4 = ell[i + 4],  t5 = ell[i + 5],  t6 = ell[i + 6],  t7 = ell[i + 7];
                int t8 = ell[i + 8],  t9 = ell[i + 9],  ta = ell[i + 10], tb = ell[i + 11];
                int tc = ell[i + 12], td = ell[i + 13], te = ell[i + 14], tf = ell[i + 15];
                float r0 = rdeg(fill[t0]), r1 = rdeg(fill[t1]), r2 = rdeg(fill[t2]), r3 = rdeg(fill[t3]);
                float r4 = rdeg(fill[t4]), r5 = rdeg(fill[t5]), r6 = rdeg(fill[t6]), r7 = rdeg(fill[t7]);
                float r8 = rdeg(fill[t8]), r9 = rdeg(fill[t9]), ra = rdeg(fill[ta]), rb = rdeg(fill[tb]);
                float rc = rdeg(fill[tc]), rd = rdeg(fill[td]), re = rdeg(fill[te]), rf = rdeg(fill[tf]);
                ushort2 u0 = ((const ushort2*)(xs + (size_t)t0 * F_IN))[lane];
                ushort2 u1 = ((const ushort2*)(xs + (size_t)t1 * F_IN))[lane];
                ushort2 u2 = ((const ushort2*)(xs + (size_t)t2 * F_IN))[lane];
                ushort2 u3 = ((const ushort2*)(xs + (size_t)t3 * F_IN))[lane];
                ushort2 u4 = ((const ushort2*)(xs + (size_t)t4 * F_IN))[lane];
                ushort2 u5 = ((const ushort2*)(xs + (size_t)t5 * F_IN))[lane];
                ushort2 u6 = ((const ushort2*)(xs + (size_t)t6 * F_IN))[lane];
                ushort2 u7 = ((const ushort2*)(xs + (size_t)t7 * F_IN))[lane];
                ushort2 u8 = ((const ushort2*)(xs + (size_t)t8 * F_IN))[lane];
                ushort2 u9 = ((const ushort2*)(xs + (size_t)t9 * F_IN))[lane];
                ushort2 ua = ((const ushort2*)(xs + (size_t)ta * F_IN))[lane];
                ushort2 ub = ((const ushort2*)(xs + (size_t)tb * F_IN))[lane];
                ushort2 uc = ((const ushort2*)(xs + (size_t)tc * F_IN))[lane];
                ushort2 ud = ((const ushort2*)(xs + (size_t)td * F_IN))[lane];
                ushort2 ue = ((const ushort2*)(xs + (size_t)te * F_IN))[lane];
                ushort2 uf = ((const ushort2*)(xs + (size_t)tf * F_IN))[lane];
                a0.x += r0 * bf2f(u0.x) + r4 * bf2f(u4.x) + r8 * bf2f(u8.x) + rc * bf2f(uc.x);
                a0.y += r0 * bf2f(u0.y) + r4 * bf2f(u4.y) + r8 * bf2f(u8.y) + rc * bf2f(uc.y);
                a1.x += r1 * bf2f(u1.x) + r5 * bf2f(u5.x) + r9 * bf2f(u9.x) + rd * bf2f(ud.x);
                a1.y += r1 * bf2f(u1.y) + r5 * bf2f(u5.y) + r9 * bf2f(u9.y) + rd * bf2f(ud.y);
                a2.x += r2 * bf2f(u2.x) + r6 * bf2f(u6.x) + ra * bf2f(ua.x) + re * bf2f(ue.x);
                a2.y += r2 * bf2f(u2.y) + r6 * bf2f(u6.y) + ra * bf2f(ua.y) + re * bf2f(ue.y);
                a3.x += r3 * bf2f(u3.x) + r7 * bf2f(u7.x) + rb * bf2f(ub.x) + rf * bf2f(uf.x);
                a3.y += r3 * bf2f(u3.y) + r7 * bf2f(u7.y) + rb * bf2f(ub.y) + rf * bf2f(uf.y);
            }
            for (; i + 8 <= end; i += 8) {
                int t0 = ell[i + 0], t1 = ell[i + 1], t2 = ell[i + 2], t3 = ell[i + 3];
                int t4 = ell[i + 4], t5 = ell[i + 5], t6 = ell[i + 6], t7 = ell[i + 7];
                float r0 = rdeg(fill[t0]), r1 = rdeg(fill[t1]);
                float r2 = rdeg(fill[t2]), r3 = rdeg(fill[t3]);
                float r4 = rdeg(fill[t4]), r5 = rdeg(fill[t5]);
                float r6 = rdeg(fill[t6]), r7 = rdeg(fill[t7]);
                ushort2 u0 = ((const ushort2*)(xs + (size_t)t0 * F_IN))[lane];
                ushort2 u1 = ((const ushort2*)(xs + (size_t)t1 * F_IN))[lane];
                ushort2 u2 = ((const ushort2*)(xs + (size_t)t2 * F_IN))[lane];
                ushort2 u3 = ((const ushort2*)(xs + (size_t)t3 * F_IN))[lane];
                ushort2 u4 = ((const ushort2*)(xs + (size_t)t4 * F_IN))[lane];
                ushort2 u5 = ((const ushort2*)(xs + (size_t)t5 * F_IN))[lane];
                ushort2 u6 = ((const ushort2*)(xs + (size_t)t6 * F_IN))[lane];
                ushort2 u7 = ((const ushort2*)(xs + (size_t)t7 * F_IN))[lane];
                a0.x += r0 * bf2f(u0.x) + r4 * bf2f(u4.x);
                a0.y += r0 * bf2f(u0.y) + r4 * bf2f(u4.y);
                a1.x += r1 * bf2f(u1.x) + r5 * bf2f(u5.x);
                a1.y += r1 * bf2f(u1.y) + r5 * bf2f(u5.y);
                a2.x += r2 * bf2f(u2.x) + r6 * bf2f(u6.x);
                a2.y += r2 * bf2f(u2.y) + r6 * bf2f(u6.y);
                a3.x += r3 * bf2f(u3.x) + r7 * bf2f(u7.x);
                a3.y += r3 * bf2f(u3.y) + r7 * bf2f(u7.y);
            }
            for (; i + 4 <= end; i += 4) {
                int t0 = ell[i + 0], t1 = ell[i + 1], t2 = ell[i + 2], t3 = ell[i + 3];
                float r0 = rdeg(fill[t0]), r1 = rdeg(fill[t1]);
                float r2 = rdeg(fill[t2]), r3 = rdeg(fill[t3]);
                ushort2 u0 = ((const ushort2*)(xs + (size_t)t0 * F_IN))[lane];
                ushort2 u1 = ((const ushort2*)(xs + (size_t)t1 * F_IN))[lane];
                ushort2 u2 = ((const ushort2*)(xs + (size_t)t2 * F_IN))[lane];
                ushort2 u3 = ((const ushort2*)(xs + (size_t)t3 * F_IN))[lane];
                a0.x += r0 * bf2f(u0.x); a0.y += r0 * bf2f(u0.y);
                a1.x += r1 * bf2f(u1.x); a1.y += r1 * bf2f(u1.y);
                a2.x += r2 * bf2f(u2.x); a2.y += r2 * bf2f(u2.y);
                a3.x += r3 * bf2f(u3.x); a3.y += r3 * bf2f(u3.y);
            }
            for (; i < end; ++i) {
                int sv = ell[i];
                float rr = rdeg(fill[sv]);
                ushort2 u = ((const ushort2*)(xs + (size_t)sv * F_IN))[lane];
                a0.x += rr * bf2f(u.x); a0.y += rr * bf2f(u.y);
            }
            ushort2 uv = ((const ushort2*)(xs + (size_t)v * F_IN))[lane];
            ob.x = f2bf(dv * (a0.x + a1.x + a2.x + a3.x + dv * bf2f(uv.x)));
            ob.y = f2bf(dv * (a0.y + a1.y + a2.y + a3.y + dv * bf2f(uv.y)));
        }
        int byteoff = (slot * 256 + lane * 4) ^ ((slot & 7) << 4);
        *(ushort2*)(Ab + byteoff) = ob;
    }
    __syncthreads();

    // ---- GEMM phase: wave w = (rowhalf = w>>2, colgrp = w&3): 16 rows x 64 cols
    const int rowhalf = w >> 2;
    const int colgrp  = w & 3;
    const int quad = lane >> 4;
    const int l15  = lane & 15;
    const int ar = rowhalf * 16 + l15;

    f32x4 acc[4];
    #pragma unroll
    for (int nt = 0; nt < 4; ++nt) acc[nt] = (f32x4){0.f, 0.f, 0.f, 0.f};

    #pragma unroll
    for (int kt = 0; kt < 4; ++kt) {
        int c = kt * 64 + quad * 16;
        bf16x8 a0 = *(const bf16x8*)(Ab + ((ar * 256 + c) ^ ((ar & 7) << 4)));
        #pragma unroll
        for (int nt = 0; nt < 4; ++nt) {
            bf16x8 b = *(const bf16x8*)(W1p + (((size_t)kt * 16 + colgrp * 4 + nt) * 64 + lane) * 8);
            acc[nt] = __builtin_amdgcn_mfma_f32_16x16x32_bf16(a0, b, acc[nt], 0, 0, 0);
        }
    }

    // C/D layout: col = lane&15, row = quad*4 + reg
    #pragma unroll
    for (int r = 0; r < 4; ++r) {
        int gm = blockIdx.x * 32 + rowhalf * 16 + quad * 4 + r;
        if (gm >= M) continue;
        float dv = rdeg(fill[gm]);
        #pragma unroll
        for (int nt = 0; nt < 4; ++nt) {
            int gn = colgrp * 64 + nt * 16 + l15;
            float s = acc[nt][r] + bias[gn];
            h1s[(size_t)gm * F_H + gn] = f2bf(fmaxf(s, 0.0f) * dv);
        }
    }
}

// ---------------------------------------------------------------- fused layer 2: gather(h1s) + MFMA + mean-pool
// Block: 32 nodes, 512 threads = 8 waves, 625 blocks. Gather 16-deep.
__global__ __launch_bounds__(512) void k_layer2(const unsigned short* __restrict__ h1s,
                                                const int* __restrict__ fill,
                                                const int* __restrict__ ell,
                                                const unsigned short* __restrict__ W2p,
                                                const float* __restrict__ bias,
                                                const int* __restrict__ batch,
                                                float* __restrict__ hg, int M) {
    __shared__ __align__(16) char smem[32 * 260 * 4];   // 33.3 KB (A-tile in first 16 KB, then sm)
    __shared__ int gb[32];
    char* Ab = smem;
    const int tid  = threadIdx.x;
    const int lane = tid & 63;
    const int w    = tid >> 6;                  // 0..7

    if (tid < 32) {
        int gm = blockIdx.x * 32 + tid;
        gb[tid] = (gm < M) ? batch[gm] : -1;
    }

    // ---- gather phase: 4 nodes per wave, lanes cover 256 feats as ushort4
    for (int s = 0; s < 4; ++s) {
        int slot = w * 4 + s;                   // 0..31
        int v = blockIdx.x * 32 + slot;
        ushort4 ob; ob.x = ob.y = ob.z = ob.w = 0;
        if (v < M) {
            int dg  = fill[v];
            int beg = v * ELL_W;
            int end = beg + min(dg, ELL_W);
            float4 a0 = make_float4(0.f, 0.f, 0.f, 0.f);
            float4 a1 = make_float4(0.f, 0.f, 0.f, 0.f);
            float4 a2 = make_float4(0.f, 0.f, 0.f, 0.f);
            float4 a3 = make_float4(0.f, 0.f, 0.f, 0.f);
            int i = beg;
            for (; i + 16 <= end; i += 16) {
                int t0 = ell[i + 0],  t1 = ell[i + 1],  t2 = ell[i + 2],  t3 = ell[i + 3];
                int t4 = ell[i + 4],  t5 = ell[i + 5],  t6 = ell[i + 6],  t7 = ell[i + 7];
                int t8 = ell[i + 8],  t9 = ell[i + 9],  ta = ell[i + 10], tb = ell[i + 11];
                int tc = ell[i + 12], td = ell[i + 13], te = ell[i + 14], tf = ell[i + 15];
                float4 h0 = ubf4(((const ushort4*)(h1s + (size_t)t0 * F_H))[lane]);
                float4 h1 = ubf4(((const ushort4*)(h1s + (size_t)t1 * F_H))[lane]);
                float4 h2 = ubf4(((const ushort4*)(h1s + (size_t)t2 * F_H))[lane]);
                float4 h3 = ubf4(((const ushort4*)(h1s + (size_t)t3 * F_H))[lane]);
                float4 h4 = ubf4(((const ushort4*)(h1s + (size_t)t4 * F_H))[lane]);
                float4 h5 = ubf4(((const ushort4*)(h1s + (size_t)t5 * F_H))[lane]);
                float4 h6 = ubf4(((const ushort4*)(h1s + (size_t)t6 * F_H))[lane]);
                float4 h7 = ubf4(((const ushort4*)(h1s + (size_t)t7 * F_H))[lane]);
                float4 h8 = ubf4(((const ushort4*)(h1s + (size_t)t8 * F_H))[lane]);
                float4 h9 = ubf4(((const ushort4*)(h1s + (size_t)t9 * F_H))[lane]);
                float4 ha = ubf4(((const ushort4*)(h1s + (size_t)ta * F_H))[lane]);
                float4 hb = ubf4(((const ushort4*)(h1s + (size_t)tb * F_H))[lane]);
                float4 hc = ubf4(((const ushort4*)(h1s + (size_t)tc * F_H))[lane]);
                float4 hd = ubf4(((const ushort4*)(h1s + (size_t)td * F_H))[lane]);
                float4 he = ubf4(((const ushort4*)(h1s + (size_t)te * F_H))[lane]);
                float4 hf = ubf4(((const ushort4*)(h1s + (size_t)tf * F_H))[lane]);
                a0.x += h0.x + h4.x + h8.x + hc.x; a0.y += h0.y + h4.y + h8.y + hc.y;
                a0.z += h0.z + h4.z + h8.z + hc.z; a0.w += h0.w + h4.w + h8.w + hc.w;
                a1.x += h1.x + h5.x + h9.x + hd.x; a1.y += h1.y + h5.y + h9.y + hd.y;
                a1.z += h1.z + h5.z + h9.z + hd.z; a1.w += h1.w + h5.w + h9.w + hd.w;
                a2.x += h2.x + h6.x + ha.x + he.x; a2.y += h2.y + h6.y + ha.y + he.y;
                a2.z += h2.z + h6.z + ha.z + he.z; a2.w += h2.w + h6.w + ha.w + he.w;
                a3.x += h3.x + h7.x + hb.x + hf.x; a3.y += h3.y + h7.y + hb.y + hf.y;
                a3.z += h3.z + h7.z + hb.z + hf.z; a3.w += h3.w + h7.w + hb.w + hf.w;
            }
            for (; i + 8 <= end; i += 8) {
                int t0 = ell[i + 0], t1 = ell[i + 1], t2 = ell[i + 2], t3 = ell[i + 3];
                int t4 = ell[i + 4], t5 = ell[i + 5], t6 = ell[i + 6], t7 = ell[i + 7];
                float4 h0 = ubf4(((const ushort4*)(h1s + (size_t)t0 * F_H))[lane]);
                float4 h1 = ubf4(((const ushort4*)(h1s + (size_t)t1 * F_H))[lane]);
                float4 h2 = ubf4(((const ushort4*)(h1s + (size_t)t2 * F_H))[lane]);
                float4 h3 = ubf4(((const ushort4*)(h1s + (size_t)t3 * F_H))[lane]);
                float4 h4 = ubf4(((const ushort4*)(h1s + (size_t)t4 * F_H))[lane]);
                float4 h5 = ubf4(((const ushort4*)(h1s + (size_t)t5 * F_H))[lane]);
                float4 h6 = ubf4(((const ushort4*)(h1s + (size_t)t6 * F_H))[lane]);
                float4 h7 = ubf4(((const ushort4*)(h1s + (size_t)t7 * F_H))[lane]);
                a0.x += h0.x + h4.x; a0.y += h0.y + h4.y; a0.z += h0.z + h4.z; a0.w += h0.w + h4.w;
                a1.x += h1.x + h5.x; a1.y += h1.y + h5.y; a1.z += h1.z + h5.z; a1.w += h1.w + h5.w;
                a2.x += h2.x + h6.x; a2.y += h2.y + h6.y; a2.z += h2.z + h6.z; a2.w += h2.w + h6.w;
                a3.x += h3.x + h7.x; a3.y += h3.y + h7.y; a3.z += h3.z + h7.z; a3.w += h3.w + h7.w;
            }
            for (; i + 4 <= end; i += 4) {
                int t0 = ell[i + 0], t1 = ell[i + 1], t2 = ell[i + 2], t3 = ell[i + 3];
                float4 h0 = ubf4(((const ushort4*)(h1s + (size_t)t0 * F_H))[lane]);
                float4 h1 = ubf4(((const ushort4*)(h1s + (size_t)t1 * F_H))[lane]);
                float4 h2 = ubf4(((const ushort4*)(h1s + (size_t)t2 * F_H))[lane]);
                float4 h3 = ubf4(((const ushort4*)(h1s + (size_t)t3 * F_H))[lane]);
                a0.x += h0.x; a0.y += h0.y; a0.z += h0.z; a0.w += h0.w;
                a1.x += h1.x; a1.y += h1.y; a1.z += h1.z; a1.w += h1.w;
                a2.x += h2.x; a2.y += h2.y; a2.z += h2.z; a2.w += h2.w;
                a3.x += h3.x; a3.y += h3.y; a3.z += h3.z; a3.w += h3.w;
            }
            for (; i < end; ++i) {
                int sv = ell[i];
                float4 h = ubf4(((const ushort4*)(h1s + (size_t)sv * F_H))[lane]);
                a0.x += h.x; a0.y += h.y; a0.z += h.z; a0.w += h.w;
            }
            float dv = rdeg(dg);
            float4 hv = ubf4(((const ushort4*)(h1s + (size_t)v * F_H))[lane]);
            ob.x = f2bf(dv * (a0.x + a1.x + a2.x + a3.x + hv.x));
            ob.y = f2bf(dv * (a0.y + a1.y + a2.y + a3.y + hv.y));
            ob.z = f2bf(dv * (a0.z + a1.z + a2.z + a3.z + hv.z));
            ob.w = f2bf(dv * (a0.w + a1.w + a2.w + a3.w + hv.w));
        }
        int byteoff = (slot * 512 + lane * 8) ^ ((slot & 7) << 4);
        *(ushort4*)(Ab + byteoff) = ob;
    }
    __syncthreads();

    // ---- GEMM phase: wave (rowhalf = w>>2, colgrp = w&3): 16 rows x 64 cols, K=256
    const int rowhalf = w >> 2;
    const int colgrp  = w & 3;
    const int quad = lane >> 4;
    const int l15  = lane & 15;
    const int ar = rowhalf * 16 + l15;

    f32x4 acc[4];
    #pragma unroll
    for (int nt = 0; nt < 4; ++nt) acc[nt] = (f32x4){0.f, 0.f, 0.f, 0.f};

    #pragma unroll
    for (int kt = 0; kt < 8; ++kt) {
        int cb = kt * 64 + quad * 16;
        bf16x8 a0 = *(const bf16x8*)(Ab + ((ar * 512 + cb) ^ ((ar & 7) << 4)));
        #pragma unroll
        for (int nt = 0; nt < 4; ++nt) {
            bf16x8 b = *(const bf16x8*)(W2p + (((size_t)kt * 16 + colgrp * 4 + nt) * 64 + lane) * 8);
            acc[nt] = __builtin_amdgcn_mfma_f32_16x16x32_bf16(a0, b, acc[nt], 0, 0, 0);
        }
    }
    __syncthreads();                       // A-tile dead; reuse smem as sm[32][260]

    // ---- relu + stage to LDS (C/D layout: col = lane&15, row = quad*4 + reg)
    float* sm = (float*)smem;
    #pragma unroll
    for (int r = 0; r < 4; ++r) {
        int wrow = rowhalf * 16 + quad * 4 + r;
        #pragma unroll
        for (int nt = 0; nt < 4; ++nt) {
            int cl = colgrp * 64 + nt * 16 + l15;
            sm[wrow * 260 + cl] = fmaxf(acc[nt][r] + bias[cl], 0.0f);
        }
    }
    __syncthreads();

    // ---- segmented per-graph pool: 512 threads = 256 cols x 2 row-chunks of 16
    int c  = tid & 255;
    int r0 = (tid >> 8) * 16;
    float s = 0.0f;
    int cur = gb[r0];
    #pragma unroll 4
    for (int r = 0; r < 16; ++r) {
        int g = gb[r0 + r];
        if (g != cur) {
            if (cur >= 0) atomicAdd(hg + (size_t)cur * F_H + c, s);
            s = 0.0f; cur = g;
        }
        s += sm[(r0 + r) * 260 + c];
    }
    if (cur >= 0) atomicAdd(hg + (size_t)cur * F_H + c, s);
}

// ---------------------------------------------------------------- fused head + dec1 + dec2
// 512 threads: every K-loop split (mu/lv 4-way, d1/d2 2-way) with LDS combine.
// R9 version was 200 blocks x 4 waves = 800 waves (0.78/SIMD) with 448 serial
// FMAs/thread -> worst-parallelized kernel. This doubles waves + halves chains.
__global__ __launch_bounds__(512) void k_head_dec(const float* __restrict__ hg,
                                                  const int* __restrict__ batch,
                                                  const float* __restrict__ Wmu,
                                                  const float* __restrict__ bmu,
                                                  const float* __restrict__ Wlv,
                                                  const float* __restrict__ blv,
                                                  const float* __restrict__ eps,
                                                  const float* __restrict__ D1,
                                                  const float* __restrict__ db1,
                                                  const float* __restrict__ D2,
                                                  const float* __restrict__ db2,
                                                  float* __restrict__ out,
                                                  unsigned short* __restrict__ d2b) {
    int g = blockIdx.x;
    int tid = threadIdx.x;
    __shared__ float hgs[F_H];
    __shared__ float pp[512];
    __shared__ float mulv[128];
    __shared__ float zs[F_L];
    __shared__ float d1s[F_H];
    __shared__ float sInv;
    if (tid == 0) {
        int lo = 0, hi = N_NODES;
        while (lo < hi) { int mid = (lo + hi) >> 1; if (batch[mid] < g) lo = mid + 1; else hi = mid; }
        int beg = lo;
        hi = N_NODES;
        while (lo < hi) { int mid = (lo + hi) >> 1; if (batch[mid] < g + 1) lo = mid + 1; else hi = mid; }
        sInv = 1.0f / fmaxf((float)(lo - beg), 1.0f);
    }
    __syncthreads();
    if (tid < F_H) hgs[tid] = hg[(size_t)g * F_H + tid] * sInv;
    __syncthreads();
    {   // mu/lv: 128 outputs x 4 K-quarters
        int o = tid & 127;             // 0..63 mu, 64..127 lv
        int q = tid >> 7;              // K quarter 0..3
        int l = o & 63;
        const float* W = (o < 64) ? Wmu : Wlv;
        float s = 0.0f;
        int k0 = q * 64;
        #pragma unroll 8
        for (int k = k0; k < k0 + 64; ++k) s += hgs[k] * W[(size_t)k * F_L + l];
        pp[tid] = s;
    }
    __syncthreads();
    if (tid < 128) {
        int l = tid & 63;
        float s = pp[tid] + pp[tid + 128] + pp[tid + 256] + pp[tid + 384]
                + ((tid < 64) ? bmu[l] : blv[l]);
        out[((tid < 64) ? MU_OFF : LV_OFF) + g * F_L + l] = s;
        mulv[tid] = s;
    }
    __syncthreads();
    if (tid < 64)
        zs[tid] = mulv[tid] + eps[g * F_L + tid] * expf(0.5f * mulv[64 + tid]);
    __syncthreads();
    {   // d1 = relu(z @ D1 + db1): 256 outputs x 2 K-halves (K=64)
        int o = tid & 255;
        int h = tid >> 8;
        float s = 0.0f;
        int k0 = h * 32;
        #pragma unroll 8
        for (int k = k0; k < k0 + 32; ++k) s += zs[k] * D1[(size_t)k * F_H + o];
        pp[tid] = s;
    }
    __syncthreads();
    if (tid < 256) d1s[tid] = fmaxf(pp[tid] + pp[tid + 256] + db1[tid], 0.0f);
    __syncthreads();
    {   // d2 = relu(d1 @ D2 + db2): 256 outputs x 2 K-halves (K=256)
        int o = tid & 255;
        int h = tid >> 8;
        float s = 0.0f;
        int k0 = h * 128;
        #pragma unroll 8
        for (int k = k0; k < k0 + 128; ++k) s += d1s[k] * D2[(size_t)k * F_H + o];
        pp[tid] = s;
    }
    __syncthreads();
    if (tid < 256)
        d2b[(size_t)g * F_H + tid] = f2bf(fmaxf(pp[tid] + pp[tid + 256] + db2[tid], 0.0f));
}

// ---------------------------------------------------------------- decoder D3 GEMM (sigmoid -> probs)
// 32-row blocks, 4 waves each own one 16-col tile: grid (78, 7) = 2184 waves.
__global__ __launch_bounds__(256) void k_gemm3(const unsigned short* __restrict__ A,
                                               const unsigned short* __restrict__ Bp,
                                               float* __restrict__ Y,
                                               const float* __restrict__ bias,
                                               int M, int N, int NP) {
    constexpr int KT = F_H / 32;
    const int NT   = NP >> 4;
    const int lane = threadIdx.x & 63;
    const int wave = threadIdx.x >> 6;
    const int bm   = blockIdx.y * 32;
    const int ng   = blockIdx.x * 4 + wave;     // one 16-col tile per wave
    const int quad = lane >> 4;
    const int l15  = lane & 15;

    int m0 = bm + l15;
    int m1 = m0 + 16;
    int m0c = min(m0, M - 1), m1c = min(m1, M - 1);

    f32x4 acc[2];
    acc[0] = (f32x4){0.f, 0.f, 0.f, 0.f};
    acc[1] = (f32x4){0.f, 0.f, 0.f, 0.f};

    #pragma unroll
    for (int kt = 0; kt < KT; ++kt) {
        bf16x8 a0 = *(const bf16x8*)(A + (size_t)m0c * F_H + kt * 32 + quad * 8);
        bf16x8 a1 = *(const bf16x8*)(A + (size_t)m1c * F_H + kt * 32 + quad * 8);
        bf16x8 b = *(const bf16x8*)(Bp + (((size_t)kt * NT + ng) * 64 + lane) * 8);
        acc[0] = __builtin_amdgcn_mfma_f32_16x16x32_bf16(a0, b, acc[0], 0, 0, 0);
        acc[1] = __builtin_amdgcn_mfma_f32_16x16x32_bf16(a1, b, acc[1], 0, 0, 0);
    }

    // C/D layout: col = lane&15, row = quad*4 + reg
    #pragma unroll
    for (int i = 0; i < 2; ++i) {
        #pragma unroll
        for (int r = 0; r < 4; ++r) {
            int gm = bm + i * 16 + quad * 4 + r;
            if (gm >= M) continue;
            int gn = (ng << 4) + l15;
            if (gn >= N) continue;
            float s = acc[i][r] + bias[gn];
            Y[(size_t)gm * N + gn] = 1.0f / (1.0f + expf(-s));
        }
    }
}

// ---------------------------------------------------------------- adjacency expansion (float4 stores)
__global__ __launch_bounds__(256) void k_adj(const float* __restrict__ probs,
                                             float* __restrict__ adj) {
    int i = blockIdx.x * blockDim.x + threadIdx.x;   // (g, a, b4): 200*100*25
    if (i >= N_GRAPHS * MAXN * (MAXN / 4)) return;
    int b4 = (i % (MAXN / 4)) * 4;
    int a  = (i / (MAXN / 4)) % MAXN;
    int g  = i / (MAXN * (MAXN / 4));
    const float* pg = probs + (size_t)g * P_PAIRS;
    float4 o;
    float* op = (float*)&o;
    #pragma unroll
    for (int c = 0; c < 4; ++c) {
        int b = b4 + c;
        float v = 0.0f;
        if (a != b) {
            int lo = min(a, b), hi = max(a, b);
            int p = lo * (MAXN - 1) - (lo * (lo - 1)) / 2 + (hi - lo - 1);
            v = pg[p];
        }
        op[c] = v;
    }
    ((float4*)adj)[i] = o;
}

// ================================================================ launch
extern "C" void kernel_launch(void* const* d_in, const int* in_sizes, int n_in,
                              void* d_out, int out_size, void* d_ws, size_t ws_size,
                              hipStream_t stream) {
    const float* x    = (const float*)d_in[0];
    const int*   eidx = (const int*)d_in[1];
    const int*   batch= (const int*)d_in[2];
    const float* eps  = (const float*)d_in[3];
    const float* W1   = (const float*)d_in[4];
    const float* b1   = (const float*)d_in[5];
    const float* W2   = (const float*)d_in[6];
    const float* b2   = (const float*)d_in[7];
    const float* Wmu  = (const float*)d_in[8];
    const float* bmu  = (const float*)d_in[9];
    const float* Wlv  = (const float*)d_in[10];
    const float* blv  = (const float*)d_in[11];
    const float* D1   = (const float*)d_in[12];
    const float* db1  = (const float*)d_in[13];
    const float* D2   = (const float*)d_in[14];
    const float* db2  = (const float*)d_in[15];
    const float* D3   = (const float*)d_in[16];
    const float* db3  = (const float*)d_in[17];

    const int* src = eidx;
    const int* dst = eidx + N_EDGES;
    float* out = (float*)d_out;

    // workspace carve-up (fill + hg contiguous -> single memset)
    char* wsb = (char*)d_ws;
    size_t o = 0;
    auto carve = [&](size_t bytes) { void* p = wsb + o; o += (bytes + 255) & ~255ull; return p; };
    int*   fill   = (int*)  carve(N_NODES * sizeof(int));                  // 80128
    float* hg     = (float*)carve((size_t)N_GRAPHS * F_H * sizeof(float)); // 204800
    int*   ell    = (int*)  carve((size_t)N_NODES * ELL_W * sizeof(int));  // 5.12 MB
    unsigned short* xs  = (unsigned short*)carve((size_t)N_NODES * F_IN * sizeof(short));
    unsigned short* W1p = (unsigned short*)carve((size_t)F_IN * F_H * sizeof(short));
    unsigned short* W2p = (unsigned short*)carve((size_t)F_H * F_H * sizeof(short));
    unsigned short* D3p = (unsigned short*)carve((size_t)F_H * P_PAD * sizeof(short));
    unsigned short* h1s = (unsigned short*)carve((size_t)N_NODES * F_H * sizeof(short));  // dinv*h1
    unsigned short* d2b = (unsigned short*)carve((size_t)N_GRAPHS * F_H * sizeof(short));
    float* probs  = (float*)carve((size_t)N_GRAPHS * P_PAIRS * sizeof(float));

    // ---- ELL build + prepack + xs cast (fill+hg zeroed in one contiguous memset)
    hipMemsetAsync(fill, 0, 284928, stream);
    k_prep<<<EF_NB + PP_NB + CV_NB, 256, 0, stream>>>(src, dst, fill, ell,
                                                      W1, W2, D3, W1p, W2p, D3p,
                                                      x, xs);

    // ---- GCN layer 1: fused gather(x) + MFMA transform (8 waves, 32-node blocks)
    k_layer1<<<ceil_div(N_NODES, 32), 512, 0, stream>>>(xs, fill, ell,
                                                        W1p, b1, h1s, N_NODES);

    // ---- GCN layer 2: fused gather(h1s) + MFMA + mean-pool sums
    k_layer2<<<ceil_div(N_NODES, 32), 512, 0, stream>>>(h1s, fill, ell,
                                                        W2p, b2, batch, hg, N_NODES);

    // ---- head/dec1/dec2 (512 threads, K-split; divides hg sums by count)
    k_head_dec<<<N_GRAPHS, 512, 0, stream>>>(hg, batch, Wmu, bmu, Wlv, blv, eps,
                                             D1, db1, D2, db2, out, d2b);

    // ---- decoder D3 (MFMA, sigmoid -> probs; 32-row blocks, wave-per-col-tile)
    {
        dim3 grid(P_PAD / 64, ceil_div(N_GRAPHS, 32));
        k_gemm3<<<grid, 256, 0, stream>>>(d2b, D3p, probs, db3,
                                          N_GRAPHS, P_PAIRS, P_PAD);
    }

    // ---- adjacency expansion (vec4)
    k_adj<<<ceil_div(N_GRAPHS * MAXN * (MAXN / 4), 256), 256, 0, stream>>>(probs, out);
}

// Round 11
// 207.592 us; speedup vs baseline: 1.0754x; 1.0754x over previous
//
#include <hip/hip_runtime.h>
#include <math.h>

#define N_NODES  20000
#define N_EDGES  320000
#define N_GRAPHS 200
#define MAXN     100
#define F_IN     128
#define F_H      256
#define F_L      64
#define P_PAIRS  4950
#define P_PAD    4992                       // P_PAIRS padded to multiple of 64
#define ADJ_SIZE (N_GRAPHS * MAXN * MAXN)   // 2,000,000
#define MU_OFF   ADJ_SIZE
#define LV_OFF   (ADJ_SIZE + N_GRAPHS * F_L)

#define ELL_W    64                         // ELL row capacity (deg ~ Poisson(16); 64 = ~12 sigma)
#define EF_NB    ((N_EDGES + 255) / 256)    // 1250 edge-fill blocks

static inline int ceil_div(int a, int b) { return (a + b - 1) / b; }

typedef __attribute__((ext_vector_type(8))) short bf16x8;   // 4 VGPRs
typedef __attribute__((ext_vector_type(4))) float f32x4;    // MFMA acc

// fp32 -> bf16 round-to-nearest-even
static __device__ inline unsigned short f2bf(float f) {
    union { float f; unsigned u; } v; v.f = f;
    unsigned r = (v.u + 0x7FFFu + ((v.u >> 16) & 1u)) >> 16;
    return (unsigned short)r;
}
static __device__ inline float bf2f(unsigned short s) {
    union { unsigned u; float f; } v; v.u = (unsigned)s << 16; return v.f;
}
static __device__ inline float4 ubf4(ushort4 u) {
    float4 f;
    f.x = bf2f(u.x); f.y = bf2f(u.y); f.z = bf2f(u.z); f.w = bf2f(u.w);
    return f;
}
static __device__ inline float rdeg(int d) { return rsqrtf((float)d + 1.0f); }  // +1 self-loop

// ---------------------------------------------------------------- fused ELL fill + weight prepack + xs cast
#define PP_S1  32768                       // W1: 128*256
#define PP_S2  98304                       // + W2: 256*256
#define PP_END 1376256                     // + D3: 256*4992
#define PP_NB  (PP_END / 256)              // 5376
#define CV_END 640000                      // N_NODES*F_IN/4 float4 elements
#define CV_NB  (CV_END / 256)              // 2500
__global__ __launch_bounds__(256) void k_prep(
        const int* __restrict__ src, const int* __restrict__ dst,
        int* __restrict__ fill, int* __restrict__ ell,
        const float* __restrict__ W1, const float* __restrict__ W2,
        const float* __restrict__ D3,
        unsigned short* __restrict__ W1p, unsigned short* __restrict__ W2p,
        unsigned short* __restrict__ D3p,
        const float* __restrict__ x, unsigned short* __restrict__ xs) {
    if (blockIdx.x < EF_NB) {
        int e = blockIdx.x * 256 + threadIdx.x;
        if (e < N_EDGES) {
            int d = dst[e];
            int pos = atomicAdd(fill + d, 1);
            if (pos < ELL_W) ell[d * ELL_W + pos] = src[e];
        }
        return;
    }
    if (blockIdx.x < EF_NB + PP_NB) {
        int pid = (blockIdx.x - EF_NB) * 256 + threadIdx.x;
        const float* W; unsigned short* Bp; int N, NP, t;
        if (pid < PP_S1)      { t = pid;          W = W1; Bp = W1p; N = 256;     NP = 256; }
        else if (pid < PP_S2) { t = pid - PP_S1;  W = W2; Bp = W2p; N = 256;     NP = 256; }
        else                  { t = pid - PP_S2;  W = D3; Bp = D3p; N = P_PAIRS; NP = P_PAD; }
        int j    = t & 7;
        int lane = (t >> 3) & 63;
        int tile = t >> 9;
        int NT = NP >> 4;
        int nt = tile % NT;
        int kt = tile / NT;
        int k = kt * 32 + (lane >> 4) * 8 + j;
        int n = nt * 16 + (lane & 15);
        Bp[t] = (n < N) ? f2bf(W[(size_t)k * N + n]) : (unsigned short)0;
        return;
    }
    int tid = (blockIdx.x - EF_NB - PP_NB) * 256 + threadIdx.x;
    if (tid >= CV_END) return;
    float4 val = ((const float4*)x)[tid];
    ushort4 o;
    o.x = f2bf(val.x); o.y = f2bf(val.y);
    o.z = f2bf(val.z); o.w = f2bf(val.w);
    ((ushort4*)xs)[tid] = o;
}

// ---------------------------------------------------------------- fused layer 1: gather(x) + MFMA
// Block: 32 nodes x 256 outputs, 512 threads = 8 waves -> 625 blocks, 5000 waves.
// Gather 8-deep (R10 lesson: 16-deep crossed the 128-VGPR occupancy cliff, +10us).
__global__ __launch_bounds__(512) void k_layer1(const unsigned short* __restrict__ xs,
                                                const int* __restrict__ fill,
                                                const int* __restrict__ ell,
                                                const unsigned short* __restrict__ W1p,
                                                const float* __restrict__ bias,
                                                unsigned short* __restrict__ h1s, int M) {
    __shared__ unsigned short At[32 * 128];     // 8 KB, byte-XOR swizzled
    char* Ab = (char*)At;
    const int tid  = threadIdx.x;
    const int lane = tid & 63;
    const int w    = tid >> 6;                  // 0..7

    // ---- gather phase: 4 nodes per wave, lanes cover 128 feats as ushort2
    for (int s = 0; s < 4; ++s) {
        int slot = w * 4 + s;                   // 0..31
        int v = blockIdx.x * 32 + slot;
        ushort2 ob; ob.x = 0; ob.y = 0;
        if (v < M) {
            int dg  = fill[v];
            int beg = v * ELL_W;
            int end = beg + min(dg, ELL_W);
            float dv = rdeg(dg);
            float2 a0 = make_float2(0.f, 0.f), a1 = make_float2(0.f, 0.f);
            int i = beg;
            for (; i + 8 <= end; i += 8) {
                int s0 = ell[i + 0], s1 = ell[i + 1], s2 = ell[i + 2], s3 = ell[i + 3];
                int s4 = ell[i + 4], s5 = ell[i + 5], s6 = ell[i + 6], s7 = ell[i + 7];
                float r0 = rdeg(fill[s0]), r1 = rdeg(fill[s1]);
                float r2 = rdeg(fill[s2]), r3 = rdeg(fill[s3]);
                float r4 = rdeg(fill[s4]), r5 = rdeg(fill[s5]);
                float r6 = rdeg(fill[s6]), r7 = rdeg(fill[s7]);
                ushort2 u0 = ((const ushort2*)(xs + (size_t)s0 * F_IN))[lane];
                ushort2 u1 = ((const ushort2*)(xs + (size_t)s1 * F_IN))[lane];
                ushort2 u2 = ((const ushort2*)(xs + (size_t)s2 * F_IN))[lane];
                ushort2 u3 = ((const ushort2*)(xs + (size_t)s3 * F_IN))[lane];
                ushort2 u4 = ((const ushort2*)(xs + (size_t)s4 * F_IN))[lane];
                ushort2 u5 = ((const ushort2*)(xs + (size_t)s5 * F_IN))[lane];
                ushort2 u6 = ((const ushort2*)(xs + (size_t)s6 * F_IN))[lane];
                ushort2 u7 = ((const ushort2*)(xs + (size_t)s7 * F_IN))[lane];
                a0.x += r0 * bf2f(u0.x) + r2 * bf2f(u2.x) + r4 * bf2f(u4.x) + r6 * bf2f(u6.x);
                a0.y += r0 * bf2f(u0.y) + r2 * bf2f(u2.y) + r4 * bf2f(u4.y) + r6 * bf2f(u6.y);
                a1.x += r1 * bf2f(u1.x) + r3 * bf2f(u3.x) + r5 * bf2f(u5.x) + r7 * bf2f(u7.x);
                a1.y += r1 * bf2f(u1.y) + r3 * bf2f(u3.y) + r5 * bf2f(u5.y) + r7 * bf2f(u7.y);
            }
            for (; i + 4 <= end; i += 4) {
                int s0 = ell[i + 0], s1 = ell[i + 1], s2 = ell[i + 2], s3 = ell[i + 3];
                float r0 = rdeg(fill[s0]), r1 = rdeg(fill[s1]);
                float r2 = rdeg(fill[s2]), r3 = rdeg(fill[s3]);
                ushort2 u0 = ((const ushort2*)(xs + (size_t)s0 * F_IN))[lane];
                ushort2 u1 = ((const ushort2*)(xs + (size_t)s1 * F_IN))[lane];
                ushort2 u2 = ((const ushort2*)(xs + (size_t)s2 * F_IN))[lane];
                ushort2 u3 = ((const ushort2*)(xs + (size_t)s3 * F_IN))[lane];
                a0.x += r0 * bf2f(u0.x) + r2 * bf2f(u2.x);
                a0.y += r0 * bf2f(u0.y) + r2 * bf2f(u2.y);
                a1.x += r1 * bf2f(u1.x) + r3 * bf2f(u3.x);
                a1.y += r1 * bf2f(u1.y) + r3 * bf2f(u3.y);
            }
            for (; i < end; ++i) {
                int sv = ell[i];
                float rr = rdeg(fill[sv]);
                ushort2 u = ((const ushort2*)(xs + (size_t)sv * F_IN))[lane];
                a0.x += rr * bf2f(u.x); a0.y += rr * bf2f(u.y);
            }
            ushort2 uv = ((const ushort2*)(xs + (size_t)v * F_IN))[lane];
            ob.x = f2bf(dv * (a0.x + a1.x + dv * bf2f(uv.x)));
            ob.y = f2bf(dv * (a0.y + a1.y + dv * bf2f(uv.y)));
        }
        int byteoff = (slot * 256 + lane * 4) ^ ((slot & 7) << 4);
        *(ushort2*)(Ab + byteoff) = ob;
    }
    __syncthreads();

    // ---- GEMM phase: wave w = (rowhalf = w>>2, colgrp = w&3): 16 rows x 64 cols
    const int rowhalf = w >> 2;
    const int colgrp  = w & 3;
    const int quad = lane >> 4;
    const int l15  = lane & 15;
    const int ar = rowhalf * 16 + l15;

    f32x4 acc[4];
    #pragma unroll
    for (int nt = 0; nt < 4; ++nt) acc[nt] = (f32x4){0.f, 0.f, 0.f, 0.f};

    #pragma unroll
    for (int kt = 0; kt < 4; ++kt) {
        int c = kt * 64 + quad * 16;
        bf16x8 a0 = *(const bf16x8*)(Ab + ((ar * 256 + c) ^ ((ar & 7) << 4)));
        #pragma unroll
        for (int nt = 0; nt < 4; ++nt) {
            bf16x8 b = *(const bf16x8*)(W1p + (((size_t)kt * 16 + colgrp * 4 + nt) * 64 + lane) * 8);
            acc[nt] = __builtin_amdgcn_mfma_f32_16x16x32_bf16(a0, b, acc[nt], 0, 0, 0);
        }
    }

    // C/D layout: col = lane&15, row = quad*4 + reg
    #pragma unroll
    for (int r = 0; r < 4; ++r) {
        int gm = blockIdx.x * 32 + rowhalf * 16 + quad * 4 + r;
        if (gm >= M) continue;
        float dv = rdeg(fill[gm]);
        #pragma unroll
        for (int nt = 0; nt < 4; ++nt) {
            int gn = colgrp * 64 + nt * 16 + l15;
            float s = acc[nt][r] + bias[gn];
            h1s[(size_t)gm * F_H + gn] = f2bf(fmaxf(s, 0.0f) * dv);
        }
    }
}

// ---------------------------------------------------------------- fused layer 2: gather(h1s) + MFMA + mean-pool
// Block: 32 nodes, 512 threads = 8 waves, 625 blocks. Gather 8-deep (R10: 16-deep = VGPR cliff).
__global__ __launch_bounds__(512) void k_layer2(const unsigned short* __restrict__ h1s,
                                                const int* __restrict__ fill,
                                                const int* __restrict__ ell,
                                                const unsigned short* __restrict__ W2p,
                                                const float* __restrict__ bias,
                                                const int* __restrict__ batch,
                                                float* __restrict__ hg, int M) {
    __shared__ __align__(16) char smem[32 * 260 * 4];   // 33.3 KB (A-tile in first 16 KB, then sm)
    __shared__ int gb[32];
    char* Ab = smem;
    const int tid  = threadIdx.x;
    const int lane = tid & 63;
    const int w    = tid >> 6;                  // 0..7

    if (tid < 32) {
        int gm = blockIdx.x * 32 + tid;
        gb[tid] = (gm < M) ? batch[gm] : -1;
    }

    // ---- gather phase: 4 nodes per wave, lanes cover 256 feats as ushort4
    for (int s = 0; s < 4; ++s) {
        int slot = w * 4 + s;                   // 0..31
        int v = blockIdx.x * 32 + slot;
        ushort4 ob; ob.x = ob.y = ob.z = ob.w = 0;
        if (v < M) {
            int dg  = fill[v];
            int beg = v * ELL_W;
            int end = beg + min(dg, ELL_W);
            float4 a0 = make_float4(0.f, 0.f, 0.f, 0.f);
            float4 a1 = make_float4(0.f, 0.f, 0.f, 0.f);
            int i = beg;
            for (; i + 8 <= end; i += 8) {
                int s0 = ell[i + 0], s1 = ell[i + 1], s2 = ell[i + 2], s3 = ell[i + 3];
                int s4 = ell[i + 4], s5 = ell[i + 5], s6 = ell[i + 6], s7 = ell[i + 7];
                float4 h0 = ubf4(((const ushort4*)(h1s + (size_t)s0 * F_H))[lane]);
                float4 h1 = ubf4(((const ushort4*)(h1s + (size_t)s1 * F_H))[lane]);
                float4 h2 = ubf4(((const ushort4*)(h1s + (size_t)s2 * F_H))[lane]);
                float4 h3 = ubf4(((const ushort4*)(h1s + (size_t)s3 * F_H))[lane]);
                float4 h4 = ubf4(((const ushort4*)(h1s + (size_t)s4 * F_H))[lane]);
                float4 h5 = ubf4(((const ushort4*)(h1s + (size_t)s5 * F_H))[lane]);
                float4 h6 = ubf4(((const ushort4*)(h1s + (size_t)s6 * F_H))[lane]);
                float4 h7 = ubf4(((const ushort4*)(h1s + (size_t)s7 * F_H))[lane]);
                a0.x += h0.x + h2.x + h4.x + h6.x; a0.y += h0.y + h2.y + h4.y + h6.y;
                a0.z += h0.z + h2.z + h4.z + h6.z; a0.w += h0.w + h2.w + h4.w + h6.w;
                a1.x += h1.x + h3.x + h5.x + h7.x; a1.y += h1.y + h3.y + h5.y + h7.y;
                a1.z += h1.z + h3.z + h5.z + h7.z; a1.w += h1.w + h3.w + h5.w + h7.w;
            }
            for (; i + 4 <= end; i += 4) {
                int s0 = ell[i + 0], s1 = ell[i + 1], s2 = ell[i + 2], s3 = ell[i + 3];
                float4 h0 = ubf4(((const ushort4*)(h1s + (size_t)s0 * F_H))[lane]);
                float4 h1 = ubf4(((const ushort4*)(h1s + (size_t)s1 * F_H))[lane]);
                float4 h2 = ubf4(((const ushort4*)(h1s + (size_t)s2 * F_H))[lane]);
                float4 h3 = ubf4(((const ushort4*)(h1s + (size_t)s3 * F_H))[lane]);
                a0.x += h0.x + h2.x; a0.y += h0.y + h2.y; a0.z += h0.z + h2.z; a0.w += h0.w + h2.w;
                a1.x += h1.x + h3.x; a1.y += h1.y + h3.y; a1.z += h1.z + h3.z; a1.w += h1.w + h3.w;
            }
            for (; i < end; ++i) {
                int sv = ell[i];
                float4 h = ubf4(((const ushort4*)(h1s + (size_t)sv * F_H))[lane]);
                a0.x += h.x; a0.y += h.y; a0.z += h.z; a0.w += h.w;
            }
            float dv = rdeg(dg);
            float4 hv = ubf4(((const ushort4*)(h1s + (size_t)v * F_H))[lane]);
            ob.x = f2bf(dv * (a0.x + a1.x + hv.x));
            ob.y = f2bf(dv * (a0.y + a1.y + hv.y));
            ob.z = f2bf(dv * (a0.z + a1.z + hv.z));
            ob.w = f2bf(dv * (a0.w + a1.w + hv.w));
        }
        int byteoff = (slot * 512 + lane * 8) ^ ((slot & 7) << 4);
        *(ushort4*)(Ab + byteoff) = ob;
    }
    __syncthreads();

    // ---- GEMM phase: wave (rowhalf = w>>2, colgrp = w&3): 16 rows x 64 cols, K=256
    const int rowhalf = w >> 2;
    const int colgrp  = w & 3;
    const int quad = lane >> 4;
    const int l15  = lane & 15;
    const int ar = rowhalf * 16 + l15;

    f32x4 acc[4];
    #pragma unroll
    for (int nt = 0; nt < 4; ++nt) acc[nt] = (f32x4){0.f, 0.f, 0.f, 0.f};

    #pragma unroll
    for (int kt = 0; kt < 8; ++kt) {
        int cb = kt * 64 + quad * 16;
        bf16x8 a0 = *(const bf16x8*)(Ab + ((ar * 512 + cb) ^ ((ar & 7) << 4)));
        #pragma unroll
        for (int nt = 0; nt < 4; ++nt) {
            bf16x8 b = *(const bf16x8*)(W2p + (((size_t)kt * 16 + colgrp * 4 + nt) * 64 + lane) * 8);
            acc[nt] = __builtin_amdgcn_mfma_f32_16x16x32_bf16(a0, b, acc[nt], 0, 0, 0);
        }
    }
    __syncthreads();                       // A-tile dead; reuse smem as sm[32][260]

    // ---- relu + stage to LDS (C/D layout: col = lane&15, row = quad*4 + reg)
    float* sm = (float*)smem;
    #pragma unroll
    for (int r = 0; r < 4; ++r) {
        int wrow = rowhalf * 16 + quad * 4 + r;
        #pragma unroll
        for (int nt = 0; nt < 4; ++nt) {
            int cl = colgrp * 64 + nt * 16 + l15;
            sm[wrow * 260 + cl] = fmaxf(acc[nt][r] + bias[cl], 0.0f);
        }
    }
    __syncthreads();

    // ---- segmented per-graph pool: 512 threads = 256 cols x 2 row-chunks of 16
    int c  = tid & 255;
    int r0 = (tid >> 8) * 16;
    float s = 0.0f;
    int cur = gb[r0];
    #pragma unroll 4
    for (int r = 0; r < 16; ++r) {
        int g = gb[r0 + r];
        if (g != cur) {
            if (cur >= 0) atomicAdd(hg + (size_t)cur * F_H + c, s);
            s = 0.0f; cur = g;
        }
        s += sm[(r0 + r) * 260 + c];
    }
    if (cur >= 0) atomicAdd(hg + (size_t)cur * F_H + c, s);
}

// ---------------------------------------------------------------- fused head + dec1 + dec2
// 512 threads: every K-loop split (mu/lv 4-way, d1/d2 2-way) with LDS combine.
// (R10 change kept in isolation: 1600 waves vs R9's 800, half the serial chains.)
__global__ __launch_bounds__(512) void k_head_dec(const float* __restrict__ hg,
                                                  const int* __restrict__ batch,
                                                  const float* __restrict__ Wmu,
                                                  const float* __restrict__ bmu,
                                                  const float* __restrict__ Wlv,
                                                  const float* __restrict__ blv,
                                                  const float* __restrict__ eps,
                                                  const float* __restrict__ D1,
                                                  const float* __restrict__ db1,
                                                  const float* __restrict__ D2,
                                                  const float* __restrict__ db2,
                                                  float* __restrict__ out,
                                                  unsigned short* __restrict__ d2b) {
    int g = blockIdx.x;
    int tid = threadIdx.x;
    __shared__ float hgs[F_H];
    __shared__ float pp[512];
    __shared__ float mulv[128];
    __shared__ float zs[F_L];
    __shared__ float d1s[F_H];
    __shared__ float sInv;
    if (tid == 0) {
        int lo = 0, hi = N_NODES;
        while (lo < hi) { int mid = (lo + hi) >> 1; if (batch[mid] < g) lo = mid + 1; else hi = mid; }
        int beg = lo;
        hi = N_NODES;
        while (lo < hi) { int mid = (lo + hi) >> 1; if (batch[mid] < g + 1) lo = mid + 1; else hi = mid; }
        sInv = 1.0f / fmaxf((float)(lo - beg), 1.0f);
    }
    __syncthreads();
    if (tid < F_H) hgs[tid] = hg[(size_t)g * F_H + tid] * sInv;
    __syncthreads();
    {   // mu/lv: 128 outputs x 4 K-quarters
        int o = tid & 127;             // 0..63 mu, 64..127 lv
        int q = tid >> 7;              // K quarter 0..3
        int l = o & 63;
        const float* W = (o < 64) ? Wmu : Wlv;
        float s = 0.0f;
        int k0 = q * 64;
        #pragma unroll 8
        for (int k = k0; k < k0 + 64; ++k) s += hgs[k] * W[(size_t)k * F_L + l];
        pp[tid] = s;
    }
    __syncthreads();
    if (tid < 128) {
        int l = tid & 63;
        float s = pp[tid] + pp[tid + 128] + pp[tid + 256] + pp[tid + 384]
                + ((tid < 64) ? bmu[l] : blv[l]);
        out[((tid < 64) ? MU_OFF : LV_OFF) + g * F_L + l] = s;
        mulv[tid] = s;
    }
    __syncthreads();
    if (tid < 64)
        zs[tid] = mulv[tid] + eps[g * F_L + tid] * expf(0.5f * mulv[64 + tid]);
    __syncthreads();
    {   // d1 = relu(z @ D1 + db1): 256 outputs x 2 K-halves (K=64)
        int o = tid & 255;
        int h = tid >> 8;
        float s = 0.0f;
        int k0 = h * 32;
        #pragma unroll 8
        for (int k = k0; k < k0 + 32; ++k) s += zs[k] * D1[(size_t)k * F_H + o];
        pp[tid] = s;
    }
    __syncthreads();
    if (tid < 256) d1s[tid] = fmaxf(pp[tid] + pp[tid + 256] + db1[tid], 0.0f);
    __syncthreads();
    {   // d2 = relu(d1 @ D2 + db2): 256 outputs x 2 K-halves (K=256)
        int o = tid & 255;
        int h = tid >> 8;
        float s = 0.0f;
        int k0 = h * 128;
        #pragma unroll 8
        for (int k = k0; k < k0 + 128; ++k) s += d1s[k] * D2[(size_t)k * F_H + o];
        pp[tid] = s;
    }
    __syncthreads();
    if (tid < 256)
        d2b[(size_t)g * F_H + tid] = f2bf(fmaxf(pp[tid] + pp[tid + 256] + db2[tid], 0.0f));
}

// ---------------------------------------------------------------- decoder D3 GEMM (sigmoid -> probs)
// 32-row blocks, 4 waves each own one 16-col tile: grid (78, 7) = 2184 waves.
__global__ __launch_bounds__(256) void k_gemm3(const unsigned short* __restrict__ A,
                                               const unsigned short* __restrict__ Bp,
                                               float* __restrict__ Y,
                                               const float* __restrict__ bias,
                                               int M, int N, int NP) {
    constexpr int KT = F_H / 32;
    const int NT   = NP >> 4;
    const int lane = threadIdx.x & 63;
    const int wave = threadIdx.x >> 6;
    const int bm   = blockIdx.y * 32;
    const int ng   = blockIdx.x * 4 + wave;     // one 16-col tile per wave
    const int quad = lane >> 4;
    const int l15  = lane & 15;

    int m0 = bm + l15;
    int m1 = m0 + 16;
    int m0c = min(m0, M - 1), m1c = min(m1, M - 1);

    f32x4 acc[2];
    acc[0] = (f32x4){0.f, 0.f, 0.f, 0.f};
    acc[1] = (f32x4){0.f, 0.f, 0.f, 0.f};

    #pragma unroll
    for (int kt = 0; kt < KT; ++kt) {
        bf16x8 a0 = *(const bf16x8*)(A + (size_t)m0c * F_H + kt * 32 + quad * 8);
        bf16x8 a1 = *(const bf16x8*)(A + (size_t)m1c * F_H + kt * 32 + quad * 8);
        bf16x8 b = *(const bf16x8*)(Bp + (((size_t)kt * NT + ng) * 64 + lane) * 8);
        acc[0] = __builtin_amdgcn_mfma_f32_16x16x32_bf16(a0, b, acc[0], 0, 0, 0);
        acc[1] = __builtin_amdgcn_mfma_f32_16x16x32_bf16(a1, b, acc[1], 0, 0, 0);
    }

    // C/D layout: col = lane&15, row = quad*4 + reg
    #pragma unroll
    for (int i = 0; i < 2; ++i) {
        #pragma unroll
        for (int r = 0; r < 4; ++r) {
            int gm = bm + i * 16 + quad * 4 + r;
            if (gm >= M) continue;
            int gn = (ng << 4) + l15;
            if (gn >= N) continue;
            float s = acc[i][r] + bias[gn];
            Y[(size_t)gm * N + gn] = 1.0f / (1.0f + expf(-s));
        }
    }
}

// ---------------------------------------------------------------- adjacency expansion (float4 stores)
__global__ __launch_bounds__(256) void k_adj(const float* __restrict__ probs,
                                             float* __restrict__ adj) {
    int i = blockIdx.x * blockDim.x + threadIdx.x;   // (g, a, b4): 200*100*25
    if (i >= N_GRAPHS * MAXN * (MAXN / 4)) return;
    int b4 = (i % (MAXN / 4)) * 4;
    int a  = (i / (MAXN / 4)) % MAXN;
    int g  = i / (MAXN * (MAXN / 4));
    const float* pg = probs + (size_t)g * P_PAIRS;
    float4 o;
    float* op = (float*)&o;
    #pragma unroll
    for (int c = 0; c < 4; ++c) {
        int b = b4 + c;
        float v = 0.0f;
        if (a != b) {
            int lo = min(a, b), hi = max(a, b);
            int p = lo * (MAXN - 1) - (lo * (lo - 1)) / 2 + (hi - lo - 1);
            v = pg[p];
        }
        op[c] = v;
    }
    ((float4*)adj)[i] = o;
}

// ================================================================ launch
extern "C" void kernel_launch(void* const* d_in, const int* in_sizes, int n_in,
                              void* d_out, int out_size, void* d_ws, size_t ws_size,
                              hipStream_t stream) {
    const float* x    = (const float*)d_in[0];
    const int*   eidx = (const int*)d_in[1];
    const int*   batch= (const int*)d_in[2];
    const float* eps  = (const float*)d_in[3];
    const float* W1   = (const float*)d_in[4];
    const float* b1   = (const float*)d_in[5];
    const float* W2   = (const float*)d_in[6];
    const float* b2   = (const float*)d_in[7];
    const float* Wmu  = (const float*)d_in[8];
    const float* bmu  = (const float*)d_in[9];
    const float* Wlv  = (const float*)d_in[10];
    const float* blv  = (const float*)d_in[11];
    const float* D1   = (const float*)d_in[12];
    const float* db1  = (const float*)d_in[13];
    const float* D2   = (const float*)d_in[14];
    const float* db2  = (const float*)d_in[15];
    const float* D3   = (const float*)d_in[16];
    const float* db3  = (const float*)d_in[17];

    const int* src = eidx;
    const int* dst = eidx + N_EDGES;
    float* out = (float*)d_out;

    // workspace carve-up (fill + hg contiguous -> single memset)
    char* wsb = (char*)d_ws;
    size_t o = 0;
    auto carve = [&](size_t bytes) { void* p = wsb + o; o += (bytes + 255) & ~255ull; return p; };
    int*   fill   = (int*)  carve(N_NODES * sizeof(int));                  // 80128
    float* hg     = (float*)carve((size_t)N_GRAPHS * F_H * sizeof(float)); // 204800
    int*   ell    = (int*)  carve((size_t)N_NODES * ELL_W * sizeof(int));  // 5.12 MB
    unsigned short* xs  = (unsigned short*)carve((size_t)N_NODES * F_IN * sizeof(short));
    unsigned short* W1p = (unsigned short*)carve((size_t)F_IN * F_H * sizeof(short));
    unsigned short* W2p = (unsigned short*)carve((size_t)F_H * F_H * sizeof(short));
    unsigned short* D3p = (unsigned short*)carve((size_t)F_H * P_PAD * sizeof(short));
    unsigned short* h1s = (unsigned short*)carve((size_t)N_NODES * F_H * sizeof(short));  // dinv*h1
    unsigned short* d2b = (unsigned short*)carve((size_t)N_GRAPHS * F_H * sizeof(short));
    float* probs  = (float*)carve((size_t)N_GRAPHS * P_PAIRS * sizeof(float));

    // ---- ELL build + prepack + xs cast (fill+hg zeroed in one contiguous memset)
    hipMemsetAsync(fill, 0, 284928, stream);
    k_prep<<<EF_NB + PP_NB + CV_NB, 256, 0, stream>>>(src, dst, fill, ell,
                                                      W1, W2, D3, W1p, W2p, D3p,
                                                      x, xs);

    // ---- GCN layer 1: fused gather(x) + MFMA transform (8 waves, 32-node blocks)
    k_layer1<<<ceil_div(N_NODES, 32), 512, 0, stream>>>(xs, fill, ell,
                                                        W1p, b1, h1s, N_NODES);

    // ---- GCN layer 2: fused gather(h1s) + MFMA + mean-pool sums
    k_layer2<<<ceil_div(N_NODES, 32), 512, 0, stream>>>(h1s, fill, ell,
                                                        W2p, b2, batch, hg, N_NODES);

    // ---- head/dec1/dec2 (512 threads, K-split; divides hg sums by count)
    k_head_dec<<<N_GRAPHS, 512, 0, stream>>>(hg, batch, Wmu, bmu, Wlv, blv, eps,
                                             D1, db1, D2, db2, out, d2b);

    // ---- decoder D3 (MFMA, sigmoid -> probs; 32-row blocks, wave-per-col-tile)
    {
        dim3 grid(P_PAD / 64, ceil_div(N_GRAPHS, 32));
        k_gemm3<<<grid, 256, 0, stream>>>(d2b, D3p, probs, db3,
                                          N_GRAPHS, P_PAIRS, P_PAD);
    }

    // ---- adjacency expansion (vec4)
    k_adj<<<ceil_div(N_GRAPHS * MAXN * (MAXN / 4), 256), 256, 0, stream>>>(probs, out);
}

// Round 12
// 204.696 us; speedup vs baseline: 1.0906x; 1.0141x over previous
//
#include <hip/hip_runtime.h>
#include <math.h>

#define N_NODES  20000
#define N_EDGES  320000
#define N_GRAPHS 200
#define MAXN     100
#define F_IN     128
#define F_H      256
#define F_L      64
#define P_PAIRS  4950
#define P_PAD    4992                       // P_PAIRS padded to multiple of 64
#define ADJ_SIZE (N_GRAPHS * MAXN * MAXN)   // 2,000,000
#define MU_OFF   ADJ_SIZE
#define LV_OFF   (ADJ_SIZE + N_GRAPHS * F_L)

#define ELL_W    64                         // ELL row capacity (deg ~ Poisson(16); 64 = ~12 sigma)
#define EF_NB    ((N_EDGES + 255) / 256)    // 1250 edge-fill blocks

static inline int ceil_div(int a, int b) { return (a + b - 1) / b; }

typedef __attribute__((ext_vector_type(8))) short bf16x8;   // 4 VGPRs
typedef __attribute__((ext_vector_type(4))) float f32x4;    // MFMA acc

// fp32 -> bf16 round-to-nearest-even
static __device__ inline unsigned short f2bf(float f) {
    union { float f; unsigned u; } v; v.f = f;
    unsigned r = (v.u + 0x7FFFu + ((v.u >> 16) & 1u)) >> 16;
    return (unsigned short)r;
}
static __device__ inline float bf2f(unsigned short s) {
    union { unsigned u; float f; } v; v.u = (unsigned)s << 16; return v.f;
}
static __device__ inline float4 ubf4(ushort4 u) {
    float4 f;
    f.x = bf2f(u.x); f.y = bf2f(u.y); f.z = bf2f(u.z); f.w = bf2f(u.w);
    return f;
}
static __device__ inline float rdeg(int d) { return rsqrtf((float)d + 1.0f); }  // +1 self-loop

// ---------------------------------------------------------------- fused ELL fill + weight prepack + xs cast
#define PP_S1  32768                       // W1: 128*256
#define PP_S2  98304                       // + W2: 256*256
#define PP_END 1376256                     // + D3: 256*4992
#define PP_NB  (PP_END / 256)              // 5376
#define CV_END 640000                      // N_NODES*F_IN/4 float4 elements
#define CV_NB  (CV_END / 256)              // 2500
__global__ __launch_bounds__(256) void k_prep(
        const int* __restrict__ src, const int* __restrict__ dst,
        int* __restrict__ fill, int* __restrict__ ell,
        const float* __restrict__ W1, const float* __restrict__ W2,
        const float* __restrict__ D3,
        unsigned short* __restrict__ W1p, unsigned short* __restrict__ W2p,
        unsigned short* __restrict__ D3p,
        const float* __restrict__ x, unsigned short* __restrict__ xs) {
    if (blockIdx.x < EF_NB) {
        int e = blockIdx.x * 256 + threadIdx.x;
        if (e < N_EDGES) {
            int d = dst[e];
            int pos = atomicAdd(fill + d, 1);
            if (pos < ELL_W) ell[d * ELL_W + pos] = src[e];
        }
        return;
    }
    if (blockIdx.x < EF_NB + PP_NB) {
        int pid = (blockIdx.x - EF_NB) * 256 + threadIdx.x;
        const float* W; unsigned short* Bp; int N, NP, t;
        if (pid < PP_S1)      { t = pid;          W = W1; Bp = W1p; N = 256;     NP = 256; }
        else if (pid < PP_S2) { t = pid - PP_S1;  W = W2; Bp = W2p; N = 256;     NP = 256; }
        else                  { t = pid - PP_S2;  W = D3; Bp = D3p; N = P_PAIRS; NP = P_PAD; }
        int j    = t & 7;
        int lane = (t >> 3) & 63;
        int tile = t >> 9;
        int NT = NP >> 4;
        int nt = tile % NT;
        int kt = tile / NT;
        int k = kt * 32 + (lane >> 4) * 8 + j;
        int n = nt * 16 + (lane & 15);
        Bp[t] = (n < N) ? f2bf(W[(size_t)k * N + n]) : (unsigned short)0;
        return;
    }
    int tid = (blockIdx.x - EF_NB - PP_NB) * 256 + threadIdx.x;
    if (tid >= CV_END) return;
    float4 val = ((const float4*)x)[tid];
    ushort4 o;
    o.x = f2bf(val.x); o.y = f2bf(val.y);
    o.z = f2bf(val.z); o.w = f2bf(val.w);
    ((ushort4*)xs)[tid] = o;
}

// ---------------------------------------------------------------- fused layer 1: gather(x) + MFMA
// Block: 16 nodes x 256 outputs, 512 threads = 8 waves -> 1250 blocks (4.88/CU).
// R11 lesson: VGPR=32 permits 4 blocks/CU (32 waves) but 625-block grid gave only
// 2.44/CU -> grid-limited. 16-node blocks saturate the occupancy cap.
// Phase 1: each wave aggregates 2 nodes into 4 KB XOR-swizzled LDS A-tile.
// Phase 2: wave w owns 32-col slice: 16 rows x 32 cols via 8 MFMA.
__global__ __launch_bounds__(512) void k_layer1(const unsigned short* __restrict__ xs,
                                                const int* __restrict__ fill,
                                                const int* __restrict__ ell,
                                                const unsigned short* __restrict__ W1p,
                                                const float* __restrict__ bias,
                                                unsigned short* __restrict__ h1s, int M) {
    __shared__ unsigned short At[16 * 128];     // 4 KB, byte-XOR swizzled
    char* Ab = (char*)At;
    const int tid  = threadIdx.x;
    const int lane = tid & 63;
    const int w    = tid >> 6;                  // 0..7

    // ---- gather phase: 2 nodes per wave, lanes cover 128 feats as ushort2
    for (int s = 0; s < 2; ++s) {
        int slot = w * 2 + s;                   // 0..15
        int v = blockIdx.x * 16 + slot;
        ushort2 ob; ob.x = 0; ob.y = 0;
        if (v < M) {
            int dg  = fill[v];
            int beg = v * ELL_W;
            int end = beg + min(dg, ELL_W);
            float dv = rdeg(dg);
            float2 a0 = make_float2(0.f, 0.f), a1 = make_float2(0.f, 0.f);
            int i = beg;
            for (; i + 8 <= end; i += 8) {
                int s0 = ell[i + 0], s1 = ell[i + 1], s2 = ell[i + 2], s3 = ell[i + 3];
                int s4 = ell[i + 4], s5 = ell[i + 5], s6 = ell[i + 6], s7 = ell[i + 7];
                float r0 = rdeg(fill[s0]), r1 = rdeg(fill[s1]);
                float r2 = rdeg(fill[s2]), r3 = rdeg(fill[s3]);
                float r4 = rdeg(fill[s4]), r5 = rdeg(fill[s5]);
                float r6 = rdeg(fill[s6]), r7 = rdeg(fill[s7]);
                ushort2 u0 = ((const ushort2*)(xs + (size_t)s0 * F_IN))[lane];
                ushort2 u1 = ((const ushort2*)(xs + (size_t)s1 * F_IN))[lane];
                ushort2 u2 = ((const ushort2*)(xs + (size_t)s2 * F_IN))[lane];
                ushort2 u3 = ((const ushort2*)(xs + (size_t)s3 * F_IN))[lane];
                ushort2 u4 = ((const ushort2*)(xs + (size_t)s4 * F_IN))[lane];
                ushort2 u5 = ((const ushort2*)(xs + (size_t)s5 * F_IN))[lane];
                ushort2 u6 = ((const ushort2*)(xs + (size_t)s6 * F_IN))[lane];
                ushort2 u7 = ((const ushort2*)(xs + (size_t)s7 * F_IN))[lane];
                a0.x += r0 * bf2f(u0.x) + r2 * bf2f(u2.x) + r4 * bf2f(u4.x) + r6 * bf2f(u6.x);
                a0.y += r0 * bf2f(u0.y) + r2 * bf2f(u2.y) + r4 * bf2f(u4.y) + r6 * bf2f(u6.y);
                a1.x += r1 * bf2f(u1.x) + r3 * bf2f(u3.x) + r5 * bf2f(u5.x) + r7 * bf2f(u7.x);
                a1.y += r1 * bf2f(u1.y) + r3 * bf2f(u3.y) + r5 * bf2f(u5.y) + r7 * bf2f(u7.y);
            }
            for (; i + 4 <= end; i += 4) {
                int s0 = ell[i + 0], s1 = ell[i + 1], s2 = ell[i + 2], s3 = ell[i + 3];
                float r0 = rdeg(fill[s0]), r1 = rdeg(fill[s1]);
                float r2 = rdeg(fill[s2]), r3 = rdeg(fill[s3]);
                ushort2 u0 = ((const ushort2*)(xs + (size_t)s0 * F_IN))[lane];
                ushort2 u1 = ((const ushort2*)(xs + (size_t)s1 * F_IN))[lane];
                ushort2 u2 = ((const ushort2*)(xs + (size_t)s2 * F_IN))[lane];
                ushort2 u3 = ((const ushort2*)(xs + (size_t)s3 * F_IN))[lane];
                a0.x += r0 * bf2f(u0.x) + r2 * bf2f(u2.x);
                a0.y += r0 * bf2f(u0.y) + r2 * bf2f(u2.y);
                a1.x += r1 * bf2f(u1.x) + r3 * bf2f(u3.x);
                a1.y += r1 * bf2f(u1.y) + r3 * bf2f(u3.y);
            }
            for (; i < end; ++i) {
                int sv = ell[i];
                float rr = rdeg(fill[sv]);
                ushort2 u = ((const ushort2*)(xs + (size_t)sv * F_IN))[lane];
                a0.x += rr * bf2f(u.x); a0.y += rr * bf2f(u.y);
            }
            ushort2 uv = ((const ushort2*)(xs + (size_t)v * F_IN))[lane];
            ob.x = f2bf(dv * (a0.x + a1.x + dv * bf2f(uv.x)));
            ob.y = f2bf(dv * (a0.y + a1.y + dv * bf2f(uv.y)));
        }
        int byteoff = (slot * 256 + lane * 4) ^ ((slot & 7) << 4);
        *(ushort2*)(Ab + byteoff) = ob;
    }
    __syncthreads();

    // ---- GEMM phase: wave w owns cols [w*32, w*32+32), all 16 rows
    const int quad = lane >> 4;
    const int l15  = lane & 15;
    const int ar = l15;

    f32x4 acc[2];
    acc[0] = (f32x4){0.f, 0.f, 0.f, 0.f};
    acc[1] = (f32x4){0.f, 0.f, 0.f, 0.f};

    #pragma unroll
    for (int kt = 0; kt < 4; ++kt) {
        int c = kt * 64 + quad * 16;
        bf16x8 a0 = *(const bf16x8*)(Ab + ((ar * 256 + c) ^ ((ar & 7) << 4)));
        #pragma unroll
        for (int nt = 0; nt < 2; ++nt) {
            bf16x8 b = *(const bf16x8*)(W1p + (((size_t)kt * 16 + w * 2 + nt) * 64 + lane) * 8);
            acc[nt] = __builtin_amdgcn_mfma_f32_16x16x32_bf16(a0, b, acc[nt], 0, 0, 0);
        }
    }

    // C/D layout: col = lane&15, row = quad*4 + reg
    #pragma unroll
    for (int r = 0; r < 4; ++r) {
        int gm = blockIdx.x * 16 + quad * 4 + r;
        if (gm >= M) continue;
        float dv = rdeg(fill[gm]);
        #pragma unroll
        for (int nt = 0; nt < 2; ++nt) {
            int gn = w * 32 + nt * 16 + l15;
            float s = acc[nt][r] + bias[gn];
            h1s[(size_t)gm * F_H + gn] = f2bf(fmaxf(s, 0.0f) * dv);
        }
    }
}

// ---------------------------------------------------------------- fused layer 2: gather(h1s) + MFMA + mean-pool
// Block: 16 nodes, 512 threads = 8 waves, 1250 blocks. A-tile 8 KB; pool matrix
// staged as bf16 (reuses A-tile region) -> ~8.8 KB LDS total (was 33.3 KB).
__global__ __launch_bounds__(512) void k_layer2(const unsigned short* __restrict__ h1s,
                                                const int* __restrict__ fill,
                                                const int* __restrict__ ell,
                                                const unsigned short* __restrict__ W2p,
                                                const float* __restrict__ bias,
                                                const int* __restrict__ batch,
                                                float* __restrict__ hg, int M) {
    __shared__ __align__(16) char smem[16 * 272 * 2];   // 8.7 KB (A-tile 8 KB overlaps)
    __shared__ int gb[16];
    char* Ab = smem;
    const int tid  = threadIdx.x;
    const int lane = tid & 63;
    const int w    = tid >> 6;                  // 0..7

    if (tid < 16) {
        int gm = blockIdx.x * 16 + tid;
        gb[tid] = (gm < M) ? batch[gm] : -1;
    }

    // ---- gather phase: 2 nodes per wave, lanes cover 256 feats as ushort4
    for (int s = 0; s < 2; ++s) {
        int slot = w * 2 + s;                   // 0..15
        int v = blockIdx.x * 16 + slot;
        ushort4 ob; ob.x = ob.y = ob.z = ob.w = 0;
        if (v < M) {
            int dg  = fill[v];
            int beg = v * ELL_W;
            int end = beg + min(dg, ELL_W);
            float4 a0 = make_float4(0.f, 0.f, 0.f, 0.f);
            float4 a1 = make_float4(0.f, 0.f, 0.f, 0.f);
            int i = beg;
            for (; i + 8 <= end; i += 8) {
                int s0 = ell[i + 0], s1 = ell[i + 1], s2 = ell[i + 2], s3 = ell[i + 3];
                int s4 = ell[i + 4], s5 = ell[i + 5], s6 = ell[i + 6], s7 = ell[i + 7];
                float4 h0 = ubf4(((const ushort4*)(h1s + (size_t)s0 * F_H))[lane]);
                float4 h1 = ubf4(((const ushort4*)(h1s + (size_t)s1 * F_H))[lane]);
                float4 h2 = ubf4(((const ushort4*)(h1s + (size_t)s2 * F_H))[lane]);
                float4 h3 = ubf4(((const ushort4*)(h1s + (size_t)s3 * F_H))[lane]);
                float4 h4 = ubf4(((const ushort4*)(h1s + (size_t)s4 * F_H))[lane]);
                float4 h5 = ubf4(((const ushort4*)(h1s + (size_t)s5 * F_H))[lane]);
                float4 h6 = ubf4(((const ushort4*)(h1s + (size_t)s6 * F_H))[lane]);
                float4 h7 = ubf4(((const ushort4*)(h1s + (size_t)s7 * F_H))[lane]);
                a0.x += h0.x + h2.x + h4.x + h6.x; a0.y += h0.y + h2.y + h4.y + h6.y;
                a0.z += h0.z + h2.z + h4.z + h6.z; a0.w += h0.w + h2.w + h4.w + h6.w;
                a1.x += h1.x + h3.x + h5.x + h7.x; a1.y += h1.y + h3.y + h5.y + h7.y;
                a1.z += h1.z + h3.z + h5.z + h7.z; a1.w += h1.w + h3.w + h5.w + h7.w;
            }
            for (; i + 4 <= end; i += 4) {
                int s0 = ell[i + 0], s1 = ell[i + 1], s2 = ell[i + 2], s3 = ell[i + 3];
                float4 h0 = ubf4(((const ushort4*)(h1s + (size_t)s0 * F_H))[lane]);
                float4 h1 = ubf4(((const ushort4*)(h1s + (size_t)s1 * F_H))[lane]);
                float4 h2 = ubf4(((const ushort4*)(h1s + (size_t)s2 * F_H))[lane]);
                float4 h3 = ubf4(((const ushort4*)(h1s + (size_t)s3 * F_H))[lane]);
                a0.x += h0.x + h2.x; a0.y += h0.y + h2.y; a0.z += h0.z + h2.z; a0.w += h0.w + h2.w;
                a1.x += h1.x + h3.x; a1.y += h1.y + h3.y; a1.z += h1.z + h3.z; a1.w += h1.w + h3.w;
            }
            for (; i < end; ++i) {
                int sv = ell[i];
                float4 h = ubf4(((const ushort4*)(h1s + (size_t)sv * F_H))[lane]);
                a0.x += h.x; a0.y += h.y; a0.z += h.z; a0.w += h.w;
            }
            float dv = rdeg(dg);
            float4 hv = ubf4(((const ushort4*)(h1s + (size_t)v * F_H))[lane]);
            ob.x = f2bf(dv * (a0.x + a1.x + hv.x));
            ob.y = f2bf(dv * (a0.y + a1.y + hv.y));
            ob.z = f2bf(dv * (a0.z + a1.z + hv.z));
            ob.w = f2bf(dv * (a0.w + a1.w + hv.w));
        }
        int byteoff = (slot * 512 + lane * 8) ^ ((slot & 7) << 4);
        *(ushort4*)(Ab + byteoff) = ob;
    }
    __syncthreads();

    // ---- GEMM phase: wave w owns cols [w*32, w*32+32), all 16 rows, K=256
    const int quad = lane >> 4;
    const int l15  = lane & 15;
    const int ar = l15;

    f32x4 acc[2];
    acc[0] = (f32x4){0.f, 0.f, 0.f, 0.f};
    acc[1] = (f32x4){0.f, 0.f, 0.f, 0.f};

    #pragma unroll
    for (int kt = 0; kt < 8; ++kt) {
        int cb = kt * 64 + quad * 16;
        bf16x8 a0 = *(const bf16x8*)(Ab + ((ar * 512 + cb) ^ ((ar & 7) << 4)));
        #pragma unroll
        for (int nt = 0; nt < 2; ++nt) {
            bf16x8 b = *(const bf16x8*)(W2p + (((size_t)kt * 16 + w * 2 + nt) * 64 + lane) * 8);
            acc[nt] = __builtin_amdgcn_mfma_f32_16x16x32_bf16(a0, b, acc[nt], 0, 0, 0);
        }
    }
    __syncthreads();                       // A-tile dead; reuse smem as bf16 sm[16][272]

    // ---- relu + stage to LDS as bf16 (C/D layout: col = lane&15, row = quad*4 + reg)
    unsigned short* sm = (unsigned short*)smem;
    #pragma unroll
    for (int r = 0; r < 4; ++r) {
        int wrow = quad * 4 + r;
        #pragma unroll
        for (int nt = 0; nt < 2; ++nt) {
            int cl = w * 32 + nt * 16 + l15;
            sm[wrow * 272 + cl] = f2bf(fmaxf(acc[nt][r] + bias[cl], 0.0f));
        }
    }
    __syncthreads();

    // ---- segmented per-graph pool: 512 threads = 256 cols x 2 row-chunks of 8
    int c  = tid & 255;
    int r0 = (tid >> 8) * 8;
    float s = 0.0f;
    int cur = gb[r0];
    #pragma unroll 4
    for (int r = 0; r < 8; ++r) {
        int g = gb[r0 + r];
        if (g != cur) {
            if (cur >= 0) atomicAdd(hg + (size_t)cur * F_H + c, s);
            s = 0.0f; cur = g;
        }
        s += bf2f(sm[(r0 + r) * 272 + c]);
    }
    if (cur >= 0) atomicAdd(hg + (size_t)cur * F_H + c, s);
}

// ---------------------------------------------------------------- fused head + dec1 + dec2
// 512 threads: every K-loop split (mu/lv 4-way, d1/d2 2-way) with LDS combine.
__global__ __launch_bounds__(512) void k_head_dec(const float* __restrict__ hg,
                                                  const int* __restrict__ batch,
                                                  const float* __restrict__ Wmu,
                                                  const float* __restrict__ bmu,
                                                  const float* __restrict__ Wlv,
                                                  const float* __restrict__ blv,
                                                  const float* __restrict__ eps,
                                                  const float* __restrict__ D1,
                                                  const float* __restrict__ db1,
                                                  const float* __restrict__ D2,
                                                  const float* __restrict__ db2,
                                                  float* __restrict__ out,
                                                  unsigned short* __restrict__ d2b) {
    int g = blockIdx.x;
    int tid = threadIdx.x;
    __shared__ float hgs[F_H];
    __shared__ float pp[512];
    __shared__ float mulv[128];
    __shared__ float zs[F_L];
    __shared__ float d1s[F_H];
    __shared__ float sInv;
    if (tid == 0) {
        int lo = 0, hi = N_NODES;
        while (lo < hi) { int mid = (lo + hi) >> 1; if (batch[mid] < g) lo = mid + 1; else hi = mid; }
        int beg = lo;
        hi = N_NODES;
        while (lo < hi) { int mid = (lo + hi) >> 1; if (batch[mid] < g + 1) lo = mid + 1; else hi = mid; }
        sInv = 1.0f / fmaxf((float)(lo - beg), 1.0f);
    }
    __syncthreads();
    if (tid < F_H) hgs[tid] = hg[(size_t)g * F_H + tid] * sInv;
    __syncthreads();
    {   // mu/lv: 128 outputs x 4 K-quarters
        int o = tid & 127;             // 0..63 mu, 64..127 lv
        int q = tid >> 7;              // K quarter 0..3
        int l = o & 63;
        const float* W = (o < 64) ? Wmu : Wlv;
        float s = 0.0f;
        int k0 = q * 64;
        #pragma unroll 8
        for (int k = k0; k < k0 + 64; ++k) s += hgs[k] * W[(size_t)k * F_L + l];
        pp[tid] = s;
    }
    __syncthreads();
    if (tid < 128) {
        int l = tid & 63;
        float s = pp[tid] + pp[tid + 128] + pp[tid + 256] + pp[tid + 384]
                + ((tid < 64) ? bmu[l] : blv[l]);
        out[((tid < 64) ? MU_OFF : LV_OFF) + g * F_L + l] = s;
        mulv[tid] = s;
    }
    __syncthreads();
    if (tid < 64)
        zs[tid] = mulv[tid] + eps[g * F_L + tid] * expf(0.5f * mulv[64 + tid]);
    __syncthreads();
    {   // d1 = relu(z @ D1 + db1): 256 outputs x 2 K-halves (K=64)
        int o = tid & 255;
        int h = tid >> 8;
        float s = 0.0f;
        int k0 = h * 32;
        #pragma unroll 8
        for (int k = k0; k < k0 + 32; ++k) s += zs[k] * D1[(size_t)k * F_H + o];
        pp[tid] = s;
    }
    __syncthreads();
    if (tid < 256) d1s[tid] = fmaxf(pp[tid] + pp[tid + 256] + db1[tid], 0.0f);
    __syncthreads();
    {   // d2 = relu(d1 @ D2 + db2): 256 outputs x 2 K-halves (K=256)
        int o = tid & 255;
        int h = tid >> 8;
        float s = 0.0f;
        int k0 = h * 128;
        #pragma unroll 8
        for (int k = k0; k < k0 + 128; ++k) s += d1s[k] * D2[(size_t)k * F_H + o];
        pp[tid] = s;
    }
    __syncthreads();
    if (tid < 256)
        d2b[(size_t)g * F_H + tid] = f2bf(fmaxf(pp[tid] + pp[tid + 256] + db2[tid], 0.0f));
}

// ---------------------------------------------------------------- decoder D3 GEMM (sigmoid -> probs)
// 32-row blocks, 4 waves each own one 16-col tile: grid (78, 7) = 2184 waves.
__global__ __launch_bounds__(256) void k_gemm3(const unsigned short* __restrict__ A,
                                               const unsigned short* __restrict__ Bp,
                                               float* __restrict__ Y,
                                               const float* __restrict__ bias,
                                               int M, int N, int NP) {
    constexpr int KT = F_H / 32;
    const int NT   = NP >> 4;
    const int lane = threadIdx.x & 63;
    const int wave = threadIdx.x >> 6;
    const int bm   = blockIdx.y * 32;
    const int ng   = blockIdx.x * 4 + wave;     // one 16-col tile per wave
    const int quad = lane >> 4;
    const int l15  = lane & 15;

    int m0 = bm + l15;
    int m1 = m0 + 16;
    int m0c = min(m0, M - 1), m1c = min(m1, M - 1);

    f32x4 acc[2];
    acc[0] = (f32x4){0.f, 0.f, 0.f, 0.f};
    acc[1] = (f32x4){0.f, 0.f, 0.f, 0.f};

    #pragma unroll
    for (int kt = 0; kt < KT; ++kt) {
        bf16x8 a0 = *(const bf16x8*)(A + (size_t)m0c * F_H + kt * 32 + quad * 8);
        bf16x8 a1 = *(const bf16x8*)(A + (size_t)m1c * F_H + kt * 32 + quad * 8);
        bf16x8 b = *(const bf16x8*)(Bp + (((size_t)kt * NT + ng) * 64 + lane) * 8);
        acc[0] = __builtin_amdgcn_mfma_f32_16x16x32_bf16(a0, b, acc[0], 0, 0, 0);
        acc[1] = __builtin_amdgcn_mfma_f32_16x16x32_bf16(a1, b, acc[1], 0, 0, 0);
    }

    // C/D layout: col = lane&15, row = quad*4 + reg
    #pragma unroll
    for (int i = 0; i < 2; ++i) {
        #pragma unroll
        for (int r = 0; r < 4; ++r) {
            int gm = bm + i * 16 + quad * 4 + r;
            if (gm >= M) continue;
            int gn = (ng << 4) + l15;
            if (gn >= N) continue;
            float s = acc[i][r] + bias[gn];
            Y[(size_t)gm * N + gn] = 1.0f / (1.0f + expf(-s));
        }
    }
}

// ---------------------------------------------------------------- adjacency expansion (float4 stores)
__global__ __launch_bounds__(256) void k_adj(const float* __restrict__ probs,
                                             float* __restrict__ adj) {
    int i = blockIdx.x * blockDim.x + threadIdx.x;   // (g, a, b4): 200*100*25
    if (i >= N_GRAPHS * MAXN * (MAXN / 4)) return;
    int b4 = (i % (MAXN / 4)) * 4;
    int a  = (i / (MAXN / 4)) % MAXN;
    int g  = i / (MAXN * (MAXN / 4));
    const float* pg = probs + (size_t)g * P_PAIRS;
    float4 o;
    float* op = (float*)&o;
    #pragma unroll
    for (int c = 0; c < 4; ++c) {
        int b = b4 + c;
        float v = 0.0f;
        if (a != b) {
            int lo = min(a, b), hi = max(a, b);
            int p = lo * (MAXN - 1) - (lo * (lo - 1)) / 2 + (hi - lo - 1);
            v = pg[p];
        }
        op[c] = v;
    }
    ((float4*)adj)[i] = o;
}

// ================================================================ launch
extern "C" void kernel_launch(void* const* d_in, const int* in_sizes, int n_in,
                              void* d_out, int out_size, void* d_ws, size_t ws_size,
                              hipStream_t stream) {
    const float* x    = (const float*)d_in[0];
    const int*   eidx = (const int*)d_in[1];
    const int*   batch= (const int*)d_in[2];
    const float* eps  = (const float*)d_in[3];
    const float* W1   = (const float*)d_in[4];
    const float* b1   = (const float*)d_in[5];
    const float* W2   = (const float*)d_in[6];
    const float* b2   = (const float*)d_in[7];
    const float* Wmu  = (const float*)d_in[8];
    const float* bmu  = (const float*)d_in[9];
    const float* Wlv  = (const float*)d_in[10];
    const float* blv  = (const float*)d_in[11];
    const float* D1   = (const float*)d_in[12];
    const float* db1  = (const float*)d_in[13];
    const float* D2   = (const float*)d_in[14];
    const float* db2  = (const float*)d_in[15];
    const float* D3   = (const float*)d_in[16];
    const float* db3  = (const float*)d_in[17];

    const int* src = eidx;
    const int* dst = eidx + N_EDGES;
    float* out = (float*)d_out;

    // workspace carve-up (fill + hg contiguous -> single memset)
    char* wsb = (char*)d_ws;
    size_t o = 0;
    auto carve = [&](size_t bytes) { void* p = wsb + o; o += (bytes + 255) & ~255ull; return p; };
    int*   fill   = (int*)  carve(N_NODES * sizeof(int));                  // 80128
    float* hg     = (float*)carve((size_t)N_GRAPHS * F_H * sizeof(float)); // 204800
    int*   ell    = (int*)  carve((size_t)N_NODES * ELL_W * sizeof(int));  // 5.12 MB
    unsigned short* xs  = (unsigned short*)carve((size_t)N_NODES * F_IN * sizeof(short));
    unsigned short* W1p = (unsigned short*)carve((size_t)F_IN * F_H * sizeof(short));
    unsigned short* W2p = (unsigned short*)carve((size_t)F_H * F_H * sizeof(short));
    unsigned short* D3p = (unsigned short*)carve((size_t)F_H * P_PAD * sizeof(short));
    unsigned short* h1s = (unsigned short*)carve((size_t)N_NODES * F_H * sizeof(short));  // dinv*h1
    unsigned short* d2b = (unsigned short*)carve((size_t)N_GRAPHS * F_H * sizeof(short));
    float* probs  = (float*)carve((size_t)N_GRAPHS * P_PAIRS * sizeof(float));

    // ---- ELL build + prepack + xs cast (fill+hg zeroed in one contiguous memset)
    hipMemsetAsync(fill, 0, 284928, stream);
    k_prep<<<EF_NB + PP_NB + CV_NB, 256, 0, stream>>>(src, dst, fill, ell,
                                                      W1, W2, D3, W1p, W2p, D3p,
                                                      x, xs);

    // ---- GCN layer 1: fused gather(x) + MFMA transform (8 waves, 16-node blocks)
    k_layer1<<<ceil_div(N_NODES, 16), 512, 0, stream>>>(xs, fill, ell,
                                                        W1p, b1, h1s, N_NODES);

    // ---- GCN layer 2: fused gather(h1s) + MFMA + mean-pool sums (16-node blocks)
    k_layer2<<<ceil_div(N_NODES, 16), 512, 0, stream>>>(h1s, fill, ell,
                                                        W2p, b2, batch, hg, N_NODES);

    // ---- head/dec1/dec2 (512 threads, K-split; divides hg sums by count)
    k_head_dec<<<N_GRAPHS, 512, 0, stream>>>(hg, batch, Wmu, bmu, Wlv, blv, eps,
                                             D1, db1, D2, db2, out, d2b);

    // ---- decoder D3 (MFMA, sigmoid -> probs; 32-row blocks, wave-per-col-tile)
    {
        dim3 grid(P_PAD / 64, ceil_div(N_GRAPHS, 32));
        k_gemm3<<<grid, 256, 0, stream>>>(d2b, D3p, probs, db3,
                                          N_GRAPHS, P_PAIRS, P_PAD);
    }

    // ---- adjacency expansion (vec4)
    k_adj<<<ceil_div(N_GRAPHS * MAXN * (MAXN / 4), 256), 256, 0, stream>>>(probs, out);
}

// Round 13
// 201.988 us; speedup vs baseline: 1.1052x; 1.0134x over previous
//
#include <hip/hip_runtime.h>
#include <math.h>

#define N_NODES  20000
#define N_EDGES  320000
#define N_GRAPHS 200
#define MAXN     100
#define F_IN     128
#define F_H      256
#define F_L      64
#define P_PAIRS  4950
#define P_PAD    4992                       // P_PAIRS padded to multiple of 64
#define ADJ_SIZE (N_GRAPHS * MAXN * MAXN)   // 2,000,000
#define MU_OFF   ADJ_SIZE
#define LV_OFF   (ADJ_SIZE + N_GRAPHS * F_L)

#define ELL_W    64                         // ELL row capacity (deg ~ Poisson(16); 64 = ~12 sigma)
#define EF_NB    ((N_EDGES + 255) / 256)    // 1250 edge-fill blocks

static inline int ceil_div(int a, int b) { return (a + b - 1) / b; }

typedef __attribute__((ext_vector_type(8))) short bf16x8;   // 4 VGPRs
typedef __attribute__((ext_vector_type(4))) float f32x4;    // MFMA acc

// fp32 -> bf16 round-to-nearest-even
static __device__ inline unsigned short f2bf(float f) {
    union { float f; unsigned u; } v; v.f = f;
    unsigned r = (v.u + 0x7FFFu + ((v.u >> 16) & 1u)) >> 16;
    return (unsigned short)r;
}
static __device__ inline float bf2f(unsigned short s) {
    union { unsigned u; float f; } v; v.u = (unsigned)s << 16; return v.f;
}
static __device__ inline float4 ubf4(ushort4 u) {
    float4 f;
    f.x = bf2f(u.x); f.y = bf2f(u.y); f.z = bf2f(u.z); f.w = bf2f(u.w);
    return f;
}
static __device__ inline float rdeg(int d) { return rsqrtf((float)d + 1.0f); }  // +1 self-loop

// ---------------------------------------------------------------- fused ELL fill + weight prepack + xs cast
#define PP_S1  32768                       // W1: 128*256
#define PP_S2  98304                       // + W2: 256*256
#define PP_END 1376256                     // + D3: 256*4992
#define PP_NB  (PP_END / 256)              // 5376
#define CV_END 640000                      // N_NODES*F_IN/4 float4 elements
#define CV_NB  (CV_END / 256)              // 2500
__global__ __launch_bounds__(256) void k_prep(
        const int* __restrict__ src, const int* __restrict__ dst,
        int* __restrict__ fill, int* __restrict__ ell,
        const float* __restrict__ W1, const float* __restrict__ W2,
        const float* __restrict__ D3,
        unsigned short* __restrict__ W1p, unsigned short* __restrict__ W2p,
        unsigned short* __restrict__ D3p,
        const float* __restrict__ x, unsigned short* __restrict__ xs) {
    if (blockIdx.x < EF_NB) {
        int e = blockIdx.x * 256 + threadIdx.x;
        if (e < N_EDGES) {
            int d = dst[e];
            int pos = atomicAdd(fill + d, 1);
            if (pos < ELL_W) ell[d * ELL_W + pos] = src[e];
        }
        return;
    }
    if (blockIdx.x < EF_NB + PP_NB) {
        int pid = (blockIdx.x - EF_NB) * 256 + threadIdx.x;
        const float* W; unsigned short* Bp; int N, NP, t;
        if (pid < PP_S1)      { t = pid;          W = W1; Bp = W1p; N = 256;     NP = 256; }
        else if (pid < PP_S2) { t = pid - PP_S1;  W = W2; Bp = W2p; N = 256;     NP = 256; }
        else                  { t = pid - PP_S2;  W = D3; Bp = D3p; N = P_PAIRS; NP = P_PAD; }
        int j    = t & 7;
        int lane = (t >> 3) & 63;
        int tile = t >> 9;
        int NT = NP >> 4;
        int nt = tile % NT;
        int kt = tile / NT;
        int k = kt * 32 + (lane >> 4) * 8 + j;
        int n = nt * 16 + (lane & 15);
        Bp[t] = (n < N) ? f2bf(W[(size_t)k * N + n]) : (unsigned short)0;
        return;
    }
    int tid = (blockIdx.x - EF_NB - PP_NB) * 256 + threadIdx.x;
    if (tid >= CV_END) return;
    float4 val = ((const float4*)x)[tid];
    ushort4 o;
    o.x = f2bf(val.x); o.y = f2bf(val.y);
    o.z = f2bf(val.z); o.w = f2bf(val.w);
    ((ushort4*)xs)[tid] = o;
}

// ---------------------------------------------------------------- fused layer 1: gather(x) + MFMA
// Block: 16 nodes x 256 outputs, 512 threads = 8 waves -> 1250 blocks (occupancy-capped).
// R12 lever: paired-row loads. Lane l loads ushort4 (8 B) at feat (l&31)*4 of
// neighbor ell[i+2p+(l>>5)] -> one instruction fetches TWO 256 B rows; 8 loads in
// flight hold 4 KB (2x R12). Halves combine via shfl_xor(32); A-tile layout unchanged.
__global__ __launch_bounds__(512) void k_layer1(const unsigned short* __restrict__ xs,
                                                const int* __restrict__ fill,
                                                const int* __restrict__ ell,
                                                const unsigned short* __restrict__ W1p,
                                                const float* __restrict__ bias,
                                                unsigned short* __restrict__ h1s, int M) {
    __shared__ unsigned short At[16 * 128];     // 4 KB, byte-XOR swizzled
    char* Ab = (char*)At;
    const int tid  = threadIdx.x;
    const int lane = tid & 63;
    const int w    = tid >> 6;                  // 0..7
    const int half = lane >> 5;                 // 0..1 (neighbor parity)
    const int fo   = (lane & 31) * 4;           // feat offset (shorts)

    // ---- gather phase: 2 nodes per wave; each load covers 2 neighbor rows
    for (int s = 0; s < 2; ++s) {
        int slot = w * 2 + s;                   // 0..15
        int v = blockIdx.x * 16 + slot;
        ushort4 ob; ob.x = ob.y = ob.z = ob.w = 0;
        if (v < M) {
            int dg  = fill[v];
            int beg = v * ELL_W;
            int end = beg + min(dg, ELL_W);
            float dv = rdeg(dg);
            float4 a = make_float4(0.f, 0.f, 0.f, 0.f);
            int i = beg;
            for (; i + 16 <= end; i += 16) {    // 8 paired loads = 16 neighbors in flight
                int e0 = ell[i +  0 + half], e1 = ell[i +  2 + half];
                int e2 = ell[i +  4 + half], e3 = ell[i +  6 + half];
                int e4 = ell[i +  8 + half], e5 = ell[i + 10 + half];
                int e6 = ell[i + 12 + half], e7 = ell[i + 14 + half];
                ushort4 u0 = *(const ushort4*)(xs + (size_t)e0 * F_IN + fo);
                ushort4 u1 = *(const ushort4*)(xs + (size_t)e1 * F_IN + fo);
                ushort4 u2 = *(const ushort4*)(xs + (size_t)e2 * F_IN + fo);
                ushort4 u3 = *(const ushort4*)(xs + (size_t)e3 * F_IN + fo);
                ushort4 u4 = *(const ushort4*)(xs + (size_t)e4 * F_IN + fo);
                ushort4 u5 = *(const ushort4*)(xs + (size_t)e5 * F_IN + fo);
                ushort4 u6 = *(const ushort4*)(xs + (size_t)e6 * F_IN + fo);
                ushort4 u7 = *(const ushort4*)(xs + (size_t)e7 * F_IN + fo);
                float r0 = rdeg(fill[e0]), r1 = rdeg(fill[e1]);
                float r2 = rdeg(fill[e2]), r3 = rdeg(fill[e3]);
                float r4 = rdeg(fill[e4]), r5 = rdeg(fill[e5]);
                float r6 = rdeg(fill[e6]), r7 = rdeg(fill[e7]);
                a.x += r0 * bf2f(u0.x) + r1 * bf2f(u1.x) + r2 * bf2f(u2.x) + r3 * bf2f(u3.x)
                     + r4 * bf2f(u4.x) + r5 * bf2f(u5.x) + r6 * bf2f(u6.x) + r7 * bf2f(u7.x);
                a.y += r0 * bf2f(u0.y) + r1 * bf2f(u1.y) + r2 * bf2f(u2.y) + r3 * bf2f(u3.y)
                     + r4 * bf2f(u4.y) + r5 * bf2f(u5.y) + r6 * bf2f(u6.y) + r7 * bf2f(u7.y);
                a.z += r0 * bf2f(u0.z) + r1 * bf2f(u1.z) + r2 * bf2f(u2.z) + r3 * bf2f(u3.z)
                     + r4 * bf2f(u4.z) + r5 * bf2f(u5.z) + r6 * bf2f(u6.z) + r7 * bf2f(u7.z);
                a.w += r0 * bf2f(u0.w) + r1 * bf2f(u1.w) + r2 * bf2f(u2.w) + r3 * bf2f(u3.w)
                     + r4 * bf2f(u4.w) + r5 * bf2f(u5.w) + r6 * bf2f(u6.w) + r7 * bf2f(u7.w);
            }
            for (; i + 8 <= end; i += 8) {      // 4 paired loads = 8 neighbors
                int e0 = ell[i + 0 + half], e1 = ell[i + 2 + half];
                int e2 = ell[i + 4 + half], e3 = ell[i + 6 + half];
                ushort4 u0 = *(const ushort4*)(xs + (size_t)e0 * F_IN + fo);
                ushort4 u1 = *(const ushort4*)(xs + (size_t)e1 * F_IN + fo);
                ushort4 u2 = *(const ushort4*)(xs + (size_t)e2 * F_IN + fo);
                ushort4 u3 = *(const ushort4*)(xs + (size_t)e3 * F_IN + fo);
                float r0 = rdeg(fill[e0]), r1 = rdeg(fill[e1]);
                float r2 = rdeg(fill[e2]), r3 = rdeg(fill[e3]);
                a.x += r0 * bf2f(u0.x) + r1 * bf2f(u1.x) + r2 * bf2f(u2.x) + r3 * bf2f(u3.x);
                a.y += r0 * bf2f(u0.y) + r1 * bf2f(u1.y) + r2 * bf2f(u2.y) + r3 * bf2f(u3.y);
                a.z += r0 * bf2f(u0.z) + r1 * bf2f(u1.z) + r2 * bf2f(u2.z) + r3 * bf2f(u3.z);
                a.w += r0 * bf2f(u0.w) + r1 * bf2f(u1.w) + r2 * bf2f(u2.w) + r3 * bf2f(u3.w);
            }
            for (; i + 2 <= end; i += 2) {      // one paired load
                int e = ell[i + half];
                ushort4 u = *(const ushort4*)(xs + (size_t)e * F_IN + fo);
                float r = rdeg(fill[e]);
                a.x += r * bf2f(u.x); a.y += r * bf2f(u.y);
                a.z += r * bf2f(u.z); a.w += r * bf2f(u.w);
            }
            if (i < end && half == 0) {         // single leftover: half 0 only
                int e = ell[i];
                ushort4 u = *(const ushort4*)(xs + (size_t)e * F_IN + fo);
                float r = rdeg(fill[e]);
                a.x += r * bf2f(u.x); a.y += r * bf2f(u.y);
                a.z += r * bf2f(u.z); a.w += r * bf2f(u.w);
            }
            // combine neighbor-parity halves (lane l <-> l^32 hold same feats)
            a.x += __shfl_xor(a.x, 32);
            a.y += __shfl_xor(a.y, 32);
            a.z += __shfl_xor(a.z, 32);
            a.w += __shfl_xor(a.w, 32);
            // self term + dinv scaling
            ushort4 uv = *(const ushort4*)(xs + (size_t)v * F_IN + fo);
            ob.x = f2bf(dv * (a.x + dv * bf2f(uv.x)));
            ob.y = f2bf(dv * (a.y + dv * bf2f(uv.y)));
            ob.z = f2bf(dv * (a.z + dv * bf2f(uv.z)));
            ob.w = f2bf(dv * (a.w + dv * bf2f(uv.w)));
        }
        if (half == 0) {                        // 32 lanes x 8 B = full 256 B row
            int byteoff = (slot * 256 + (lane & 31) * 8) ^ ((slot & 7) << 4);
            *(ushort4*)(Ab + byteoff) = ob;
        }
    }
    __syncthreads();

    // ---- GEMM phase: wave w owns cols [w*32, w*32+32), all 16 rows
    const int quad = lane >> 4;
    const int l15  = lane & 15;
    const int ar = l15;

    f32x4 acc[2];
    acc[0] = (f32x4){0.f, 0.f, 0.f, 0.f};
    acc[1] = (f32x4){0.f, 0.f, 0.f, 0.f};

    #pragma unroll
    for (int kt = 0; kt < 4; ++kt) {
        int c = kt * 64 + quad * 16;
        bf16x8 a0 = *(const bf16x8*)(Ab + ((ar * 256 + c) ^ ((ar & 7) << 4)));
        #pragma unroll
        for (int nt = 0; nt < 2; ++nt) {
            bf16x8 b = *(const bf16x8*)(W1p + (((size_t)kt * 16 + w * 2 + nt) * 64 + lane) * 8);
            acc[nt] = __builtin_amdgcn_mfma_f32_16x16x32_bf16(a0, b, acc[nt], 0, 0, 0);
        }
    }

    // C/D layout: col = lane&15, row = quad*4 + reg
    #pragma unroll
    for (int r = 0; r < 4; ++r) {
        int gm = blockIdx.x * 16 + quad * 4 + r;
        if (gm >= M) continue;
        float dv = rdeg(fill[gm]);
        #pragma unroll
        for (int nt = 0; nt < 2; ++nt) {
            int gn = w * 32 + nt * 16 + l15;
            float s = acc[nt][r] + bias[gn];
            h1s[(size_t)gm * F_H + gn] = f2bf(fmaxf(s, 0.0f) * dv);
        }
    }
}

// ---------------------------------------------------------------- fused layer 2: gather(h1s) + MFMA + mean-pool
// Block: 16 nodes, 512 threads = 8 waves, 1250 blocks. 8-deep ushort4 gather
// (paired-row variant would cross the 64-VGPR cliff -- R10 lesson; left alone).
__global__ __launch_bounds__(512) void k_layer2(const unsigned short* __restrict__ h1s,
                                                const int* __restrict__ fill,
                                                const int* __restrict__ ell,
                                                const unsigned short* __restrict__ W2p,
                                                const float* __restrict__ bias,
                                                const int* __restrict__ batch,
                                                float* __restrict__ hg, int M) {
    __shared__ __align__(16) char smem[16 * 272 * 2];   // 8.7 KB (A-tile 8 KB overlaps)
    __shared__ int gb[16];
    char* Ab = smem;
    const int tid  = threadIdx.x;
    const int lane = tid & 63;
    const int w    = tid >> 6;                  // 0..7

    if (tid < 16) {
        int gm = blockIdx.x * 16 + tid;
        gb[tid] = (gm < M) ? batch[gm] : -1;
    }

    // ---- gather phase: 2 nodes per wave, lanes cover 256 feats as ushort4
    for (int s = 0; s < 2; ++s) {
        int slot = w * 2 + s;                   // 0..15
        int v = blockIdx.x * 16 + slot;
        ushort4 ob; ob.x = ob.y = ob.z = ob.w = 0;
        if (v < M) {
            int dg  = fill[v];
            int beg = v * ELL_W;
            int end = beg + min(dg, ELL_W);
            float4 a0 = make_float4(0.f, 0.f, 0.f, 0.f);
            float4 a1 = make_float4(0.f, 0.f, 0.f, 0.f);
            int i = beg;
            for (; i + 8 <= end; i += 8) {
                int s0 = ell[i + 0], s1 = ell[i + 1], s2 = ell[i + 2], s3 = ell[i + 3];
                int s4 = ell[i + 4], s5 = ell[i + 5], s6 = ell[i + 6], s7 = ell[i + 7];
                float4 h0 = ubf4(((const ushort4*)(h1s + (size_t)s0 * F_H))[lane]);
                float4 h1 = ubf4(((const ushort4*)(h1s + (size_t)s1 * F_H))[lane]);
                float4 h2 = ubf4(((const ushort4*)(h1s + (size_t)s2 * F_H))[lane]);
                float4 h3 = ubf4(((const ushort4*)(h1s + (size_t)s3 * F_H))[lane]);
                float4 h4 = ubf4(((const ushort4*)(h1s + (size_t)s4 * F_H))[lane]);
                float4 h5 = ubf4(((const ushort4*)(h1s + (size_t)s5 * F_H))[lane]);
                float4 h6 = ubf4(((const ushort4*)(h1s + (size_t)s6 * F_H))[lane]);
                float4 h7 = ubf4(((const ushort4*)(h1s + (size_t)s7 * F_H))[lane]);
                a0.x += h0.x + h2.x + h4.x + h6.x; a0.y += h0.y + h2.y + h4.y + h6.y;
                a0.z += h0.z + h2.z + h4.z + h6.z; a0.w += h0.w + h2.w + h4.w + h6.w;
                a1.x += h1.x + h3.x + h5.x + h7.x; a1.y += h1.y + h3.y + h5.y + h7.y;
                a1.z += h1.z + h3.z + h5.z + h7.z; a1.w += h1.w + h3.w + h5.w + h7.w;
            }
            for (; i + 4 <= end; i += 4) {
                int s0 = ell[i + 0], s1 = ell[i + 1], s2 = ell[i + 2], s3 = ell[i + 3];
                float4 h0 = ubf4(((const ushort4*)(h1s + (size_t)s0 * F_H))[lane]);
                float4 h1 = ubf4(((const ushort4*)(h1s + (size_t)s1 * F_H))[lane]);
                float4 h2 = ubf4(((const ushort4*)(h1s + (size_t)s2 * F_H))[lane]);
                float4 h3 = ubf4(((const ushort4*)(h1s + (size_t)s3 * F_H))[lane]);
                a0.x += h0.x + h2.x; a0.y += h0.y + h2.y; a0.z += h0.z + h2.z; a0.w += h0.w + h2.w;
                a1.x += h1.x + h3.x; a1.y += h1.y + h3.y; a1.z += h1.z + h3.z; a1.w += h1.w + h3.w;
            }
            for (; i < end; ++i) {
                int sv = ell[i];
                float4 h = ubf4(((const ushort4*)(h1s + (size_t)sv * F_H))[lane]);
                a0.x += h.x; a0.y += h.y; a0.z += h.z; a0.w += h.w;
            }
            float dv = rdeg(dg);
            float4 hv = ubf4(((const ushort4*)(h1s + (size_t)v * F_H))[lane]);
            ob.x = f2bf(dv * (a0.x + a1.x + hv.x));
            ob.y = f2bf(dv * (a0.y + a1.y + hv.y));
            ob.z = f2bf(dv * (a0.z + a1.z + hv.z));
            ob.w = f2bf(dv * (a0.w + a1.w + hv.w));
        }
        int byteoff = (slot * 512 + lane * 8) ^ ((slot & 7) << 4);
        *(ushort4*)(Ab + byteoff) = ob;
    }
    __syncthreads();

    // ---- GEMM phase: wave w owns cols [w*32, w*32+32), all 16 rows, K=256
    const int quad = lane >> 4;
    const int l15  = lane & 15;
    const int ar = l15;

    f32x4 acc[2];
    acc[0] = (f32x4){0.f, 0.f, 0.f, 0.f};
    acc[1] = (f32x4){0.f, 0.f, 0.f, 0.f};

    #pragma unroll
    for (int kt = 0; kt < 8; ++kt) {
        int cb = kt * 64 + quad * 16;
        bf16x8 a0 = *(const bf16x8*)(Ab + ((ar * 512 + cb) ^ ((ar & 7) << 4)));
        #pragma unroll
        for (int nt = 0; nt < 2; ++nt) {
            bf16x8 b = *(const bf16x8*)(W2p + (((size_t)kt * 16 + w * 2 + nt) * 64 + lane) * 8);
            acc[nt] = __builtin_amdgcn_mfma_f32_16x16x32_bf16(a0, b, acc[nt], 0, 0, 0);
        }
    }
    __syncthreads();                       // A-tile dead; reuse smem as bf16 sm[16][272]

    // ---- relu + stage to LDS as bf16 (C/D layout: col = lane&15, row = quad*4 + reg)
    unsigned short* sm = (unsigned short*)smem;
    #pragma unroll
    for (int r = 0; r < 4; ++r) {
        int wrow = quad * 4 + r;
        #pragma unroll
        for (int nt = 0; nt < 2; ++nt) {
            int cl = w * 32 + nt * 16 + l15;
            sm[wrow * 272 + cl] = f2bf(fmaxf(acc[nt][r] + bias[cl], 0.0f));
        }
    }
    __syncthreads();

    // ---- segmented per-graph pool: 512 threads = 256 cols x 2 row-chunks of 8
    int c  = tid & 255;
    int r0 = (tid >> 8) * 8;
    float s = 0.0f;
    int cur = gb[r0];
    #pragma unroll 4
    for (int r = 0; r < 8; ++r) {
        int g = gb[r0 + r];
        if (g != cur) {
            if (cur >= 0) atomicAdd(hg + (size_t)cur * F_H + c, s);
            s = 0.0f; cur = g;
        }
        s += bf2f(sm[(r0 + r) * 272 + c]);
    }
    if (cur >= 0) atomicAdd(hg + (size_t)cur * F_H + c, s);
}

// ---------------------------------------------------------------- fused head + dec1 + dec2
// 512 threads: every K-loop split (mu/lv 4-way, d1/d2 2-way) with LDS combine.
__global__ __launch_bounds__(512) void k_head_dec(const float* __restrict__ hg,
                                                  const int* __restrict__ batch,
                                                  const float* __restrict__ Wmu,
                                                  const float* __restrict__ bmu,
                                                  const float* __restrict__ Wlv,
                                                  const float* __restrict__ blv,
                                                  const float* __restrict__ eps,
                                                  const float* __restrict__ D1,
                                                  const float* __restrict__ db1,
                                                  const float* __restrict__ D2,
                                                  const float* __restrict__ db2,
                                                  float* __restrict__ out,
                                                  unsigned short* __restrict__ d2b) {
    int g = blockIdx.x;
    int tid = threadIdx.x;
    __shared__ float hgs[F_H];
    __shared__ float pp[512];
    __shared__ float mulv[128];
    __shared__ float zs[F_L];
    __shared__ float d1s[F_H];
    __shared__ float sInv;
    if (tid == 0) {
        int lo = 0, hi = N_NODES;
        while (lo < hi) { int mid = (lo + hi) >> 1; if (batch[mid] < g) lo = mid + 1; else hi = mid; }
        int beg = lo;
        hi = N_NODES;
        while (lo < hi) { int mid = (lo + hi) >> 1; if (batch[mid] < g + 1) lo = mid + 1; else hi = mid; }
        sInv = 1.0f / fmaxf((float)(lo - beg), 1.0f);
    }
    __syncthreads();
    if (tid < F_H) hgs[tid] = hg[(size_t)g * F_H + tid] * sInv;
    __syncthreads();
    {   // mu/lv: 128 outputs x 4 K-quarters
        int o = tid & 127;             // 0..63 mu, 64..127 lv
        int q = tid >> 7;              // K quarter 0..3
        int l = o & 63;
        const float* W = (o < 64) ? Wmu : Wlv;
        float s = 0.0f;
        int k0 = q * 64;
        #pragma unroll 8
        for (int k = k0; k < k0 + 64; ++k) s += hgs[k] * W[(size_t)k * F_L + l];
        pp[tid] = s;
    }
    __syncthreads();
    if (tid < 128) {
        int l = tid & 63;
        float s = pp[tid] + pp[tid + 128] + pp[tid + 256] + pp[tid + 384]
                + ((tid < 64) ? bmu[l] : blv[l]);
        out[((tid < 64) ? MU_OFF : LV_OFF) + g * F_L + l] = s;
        mulv[tid] = s;
    }
    __syncthreads();
    if (tid < 64)
        zs[tid] = mulv[tid] + eps[g * F_L + tid] * expf(0.5f * mulv[64 + tid]);
    __syncthreads();
    {   // d1 = relu(z @ D1 + db1): 256 outputs x 2 K-halves (K=64)
        int o = tid & 255;
        int h = tid >> 8;
        float s = 0.0f;
        int k0 = h * 32;
        #pragma unroll 8
        for (int k = k0; k < k0 + 32; ++k) s += zs[k] * D1[(size_t)k * F_H + o];
        pp[tid] = s;
    }
    __syncthreads();
    if (tid < 256) d1s[tid] = fmaxf(pp[tid] + pp[tid + 256] + db1[tid], 0.0f);
    __syncthreads();
    {   // d2 = relu(d1 @ D2 + db2): 256 outputs x 2 K-halves (K=256)
        int o = tid & 255;
        int h = tid >> 8;
        float s = 0.0f;
        int k0 = h * 128;
        #pragma unroll 8
        for (int k = k0; k < k0 + 128; ++k) s += d1s[k] * D2[(size_t)k * F_H + o];
        pp[tid] = s;
    }
    __syncthreads();
    if (tid < 256)
        d2b[(size_t)g * F_H + tid] = f2bf(fmaxf(pp[tid] + pp[tid + 256] + db2[tid], 0.0f));
}

// ---------------------------------------------------------------- decoder D3 GEMM (sigmoid -> probs)
// 32-row blocks, 4 waves each own one 16-col tile: grid (78, 7) = 2184 waves.
__global__ __launch_bounds__(256) void k_gemm3(const unsigned short* __restrict__ A,
                                               const unsigned short* __restrict__ Bp,
                                               float* __restrict__ Y,
                                               const float* __restrict__ bias,
                                               int M, int N, int NP) {
    constexpr int KT = F_H / 32;
    const int NT   = NP >> 4;
    const int lane = threadIdx.x & 63;
    const int wave = threadIdx.x >> 6;
    const int bm   = blockIdx.y * 32;
    const int ng   = blockIdx.x * 4 + wave;     // one 16-col tile per wave
    const int quad = lane >> 4;
    const int l15  = lane & 15;

    int m0 = bm + l15;
    int m1 = m0 + 16;
    int m0c = min(m0, M - 1), m1c = min(m1, M - 1);

    f32x4 acc[2];
    acc[0] = (f32x4){0.f, 0.f, 0.f, 0.f};
    acc[1] = (f32x4){0.f, 0.f, 0.f, 0.f};

    #pragma unroll
    for (int kt = 0; kt < KT; ++kt) {
        bf16x8 a0 = *(const bf16x8*)(A + (size_t)m0c * F_H + kt * 32 + quad * 8);
        bf16x8 a1 = *(const bf16x8*)(A + (size_t)m1c * F_H + kt * 32 + quad * 8);
        bf16x8 b = *(const bf16x8*)(Bp + (((size_t)kt * NT + ng) * 64 + lane) * 8);
        acc[0] = __builtin_amdgcn_mfma_f32_16x16x32_bf16(a0, b, acc[0], 0, 0, 0);
        acc[1] = __builtin_amdgcn_mfma_f32_16x16x32_bf16(a1, b, acc[1], 0, 0, 0);
    }

    // C/D layout: col = lane&15, row = quad*4 + reg
    #pragma unroll
    for (int i = 0; i < 2; ++i) {
        #pragma unroll
        for (int r = 0; r < 4; ++r) {
            int gm = bm + i * 16 + quad * 4 + r;
            if (gm >= M) continue;
            int gn = (ng << 4) + l15;
            if (gn >= N) continue;
            float s = acc[i][r] + bias[gn];
            Y[(size_t)gm * N + gn] = 1.0f / (1.0f + expf(-s));
        }
    }
}

// ---------------------------------------------------------------- adjacency expansion (float4 stores)
__global__ __launch_bounds__(256) void k_adj(const float* __restrict__ probs,
                                             float* __restrict__ adj) {
    int i = blockIdx.x * blockDim.x + threadIdx.x;   // (g, a, b4): 200*100*25
    if (i >= N_GRAPHS * MAXN * (MAXN / 4)) return;
    int b4 = (i % (MAXN / 4)) * 4;
    int a  = (i / (MAXN / 4)) % MAXN;
    int g  = i / (MAXN * (MAXN / 4));
    const float* pg = probs + (size_t)g * P_PAIRS;
    float4 o;
    float* op = (float*)&o;
    #pragma unroll
    for (int c = 0; c < 4; ++c) {
        int b = b4 + c;
        float v = 0.0f;
        if (a != b) {
            int lo = min(a, b), hi = max(a, b);
            int p = lo * (MAXN - 1) - (lo * (lo - 1)) / 2 + (hi - lo - 1);
            v = pg[p];
        }
        op[c] = v;
    }
    ((float4*)adj)[i] = o;
}

// ================================================================ launch
extern "C" void kernel_launch(void* const* d_in, const int* in_sizes, int n_in,
                              void* d_out, int out_size, void* d_ws, size_t ws_size,
                              hipStream_t stream) {
    const float* x    = (const float*)d_in[0];
    const int*   eidx = (const int*)d_in[1];
    const int*   batch= (const int*)d_in[2];
    const float* eps  = (const float*)d_in[3];
    const float* W1   = (const float*)d_in[4];
    const float* b1   = (const float*)d_in[5];
    const float* W2   = (const float*)d_in[6];
    const float* b2   = (const float*)d_in[7];
    const float* Wmu  = (const float*)d_in[8];
    const float* bmu  = (const float*)d_in[9];
    const float* Wlv  = (const float*)d_in[10];
    const float* blv  = (const float*)d_in[11];
    const float* D1   = (const float*)d_in[12];
    const float* db1  = (const float*)d_in[13];
    const float* D2   = (const float*)d_in[14];
    const float* db2  = (const float*)d_in[15];
    const float* D3   = (const float*)d_in[16];
    const float* db3  = (const float*)d_in[17];

    const int* src = eidx;
    const int* dst = eidx + N_EDGES;
    float* out = (float*)d_out;

    // workspace carve-up (fill + hg contiguous -> single memset)
    char* wsb = (char*)d_ws;
    size_t o = 0;
    auto carve = [&](size_t bytes) { void* p = wsb + o; o += (bytes + 255) & ~255ull; return p; };
    int*   fill   = (int*)  carve(N_NODES * sizeof(int));                  // 80128
    float* hg     = (float*)carve((size_t)N_GRAPHS * F_H * sizeof(float)); // 204800
    int*   ell    = (int*)  carve((size_t)N_NODES * ELL_W * sizeof(int));  // 5.12 MB
    unsigned short* xs  = (unsigned short*)carve((size_t)N_NODES * F_IN * sizeof(short));
    unsigned short* W1p = (unsigned short*)carve((size_t)F_IN * F_H * sizeof(short));
    unsigned short* W2p = (unsigned short*)carve((size_t)F_H * F_H * sizeof(short));
    unsigned short* D3p = (unsigned short*)carve((size_t)F_H * P_PAD * sizeof(short));
    unsigned short* h1s = (unsigned short*)carve((size_t)N_NODES * F_H * sizeof(short));  // dinv*h1
    unsigned short* d2b = (unsigned short*)carve((size_t)N_GRAPHS * F_H * sizeof(short));
    float* probs  = (float*)carve((size_t)N_GRAPHS * P_PAIRS * sizeof(float));

    // ---- ELL build + prepack + xs cast (fill+hg zeroed in one contiguous memset)
    hipMemsetAsync(fill, 0, 284928, stream);
    k_prep<<<EF_NB + PP_NB + CV_NB, 256, 0, stream>>>(src, dst, fill, ell,
                                                      W1, W2, D3, W1p, W2p, D3p,
                                                      x, xs);

    // ---- GCN layer 1: fused gather(x) + MFMA transform (paired-row loads)
    k_layer1<<<ceil_div(N_NODES, 16), 512, 0, stream>>>(xs, fill, ell,
                                                        W1p, b1, h1s, N_NODES);

    // ---- GCN layer 2: fused gather(h1s) + MFMA + mean-pool sums (16-node blocks)
    k_layer2<<<ceil_div(N_NODES, 16), 512, 0, stream>>>(h1s, fill, ell,
                                                        W2p, b2, batch, hg, N_NODES);

    // ---- head/dec1/dec2 (512 threads, K-split; divides hg sums by count)
    k_head_dec<<<N_GRAPHS, 512, 0, stream>>>(hg, batch, Wmu, bmu, Wlv, blv, eps,
                                             D1, db1, D2, db2, out, d2b);

    // ---- decoder D3 (MFMA, sigmoid -> probs; 32-row blocks, wave-per-col-tile)
    {
        dim3 grid(P_PAD / 64, ceil_div(N_GRAPHS, 32));
        k_gemm3<<<grid, 256, 0, stream>>>(d2b, D3p, probs, db3,
                                          N_GRAPHS, P_PAIRS, P_PAD);
    }

    // ---- adjacency expansion (vec4)
    k_adj<<<ceil_div(N_GRAPHS * MAXN * (MAXN / 4), 256), 256, 0, stream>>>(probs, out);
}